// Round 9
// baseline (140.885 us; speedup 1.0000x reference)
//
#include <hip/hip_runtime.h>
#include <hip/hip_bf16.h>

typedef __hip_bfloat16 bf16;
typedef __attribute__((ext_vector_type(8))) __bf16 bf16x8;
typedef __attribute__((ext_vector_type(4))) float f32x4;

#define DIM   512
#define NH    8
#define HDIM  64
#define LIND  1536
#define LSEQ  2048
#define ROWS  4096        // B*L
#define TF    128         // time features
#define KCH   32          // wpart split-K chunks
#define TCH   64          // t per chunk

__device__ __forceinline__ float b2f(bf16 v){ return __bfloat162float(v); }
__device__ __forceinline__ void stc(float* C, size_t i, float v){ C[i] = v; }
__device__ __forceinline__ void stc(bf16*  C, size_t i, float v){ C[i] = __float2bfloat16(v); }

typedef const __attribute__((address_space(1))) unsigned int* gp1_t;
typedef __attribute__((address_space(3))) unsigned int* lp3_t;
__device__ __forceinline__ void gload16(const bf16* g, unsigned short* l) {
    __builtin_amdgcn_global_load_lds((gp1_t)(const void*)g, (lp3_t)(void*)l, 16, 0, 0);
}

// ---------- setup: tensor->bf16 | time features | 5 weight transposes ----------
__global__ __launch_bounds__(256) void setup_kernel(const float* __restrict__ tensor,
                                                    const float* __restrict__ tang,
                                                    const float* __restrict__ htd,
                                                    const float* __restrict__ Qw,
                                                    const float* __restrict__ Vw,
                                                    const float* __restrict__ Ow,
                                                    const float* __restrict__ Win,
                                                    const float* __restrict__ Wout,
                                                    bf16* __restrict__ tensorb,
                                                    bf16* __restrict__ timef,
                                                    bf16* __restrict__ QwT,
                                                    bf16* __restrict__ VwT,
                                                    bf16* __restrict__ OwT,
                                                    bf16* __restrict__ WinT,
                                                    bf16* __restrict__ WoutT)
{
    int id = blockIdx.x;
    if (id < 2048) {
        int i = id * 256 + threadIdx.x;
        float4 v = ((const float4*)tensor)[i];
        bf16 t[4];
        t[0] = __float2bfloat16(v.x); t[1] = __float2bfloat16(v.y);
        t[2] = __float2bfloat16(v.z); t[3] = __float2bfloat16(v.w);
        *(uint2*)&tensorb[(size_t)i * 4] = *(uint2*)t;
        return;
    }
    if (id < 6144) {
        int idx = (id - 2048) * 256 + threadIdx.x;   // < 1048576
        int d = idx & 63;
        int h = (idx >> 6) & 7;
        int l = idx >> 9;
        float ang = ((float)l + htd[h]) * tang[h * 64 + d];
        float s, c;
        sincosf(ang, &s, &c);
        bf16* p = timef + ((size_t)l * NH + h) * TF;
        p[d]      = __float2bfloat16((c + s) * 0.125f);
        p[d + 64] = __float2bfloat16((c - s) * 0.125f);
        return;
    }
    id -= 6144;
    const float* in; bf16* out; int R, C, tx, ty;
    if (id < 256)        { in = Qw;   out = QwT;   R = 512;  C = 512;  tx = id & 15; ty = id >> 4; }
    else if (id < 512)   { id -= 256;  in = Vw;   out = VwT;   R = 512;  C = 512;  tx = id & 15; ty = id >> 4; }
    else if (id < 768)   { id -= 512;  in = Ow;   out = OwT;   R = 512;  C = 512;  tx = id & 15; ty = id >> 4; }
    else if (id < 1536)  { id -= 768;  in = Win;  out = WinT;  R = 512;  C = 1536; tx = id % 48; ty = id / 48; }
    else                 { id -= 1536; in = Wout; out = WoutT; R = 1536; C = 512;  tx = id & 15; ty = id >> 4; }

    __shared__ float t[32][33];
    int bx = tx * 32, by = ty * 32;
    int x = threadIdx.x & 31, y = threadIdx.x >> 5;
    #pragma unroll
    for (int r = 0; r < 32; r += 8)
        t[y + r][x] = in[(size_t)(by + y + r) * C + bx + x];
    __syncthreads();
    #pragma unroll
    for (int r = 0; r < 32; r += 8)
        out[(size_t)(bx + y + r) * R + by + x] = __float2bfloat16(t[x][y + r]);
}

// ===== BK=64 double-buffered MFMA GEMM (both-sides XOR swizzle) =====
// LDS tile [rows][64 k]; staging slot e: row=e>>3, granule g=e&7 holds global
// granule g^(row&7); reads XOR identically -> conflict-free (2-way alias only).
// 4 waves 2x2; wave tile (BM/2)x(BN/2); RM=BM/32, RN=BN/32 frags.

// ---------------- generic GEMM: C = epi(A[M,K] @ Bt[N,K]^T) ----------------
// EPI: 2 = x+b+res (O)   3 = gelu(x+b) (FFN1)   4 = x+b+res (FFN2)
template<int BM, int BN, int EPI, typename OUTT>
__global__ __launch_bounds__(256) void gemm_big(const bf16* __restrict__ A,
                                                const bf16* __restrict__ Bt,
                                                const float* __restrict__ bias,
                                                const float* __restrict__ res,
                                                OUTT* __restrict__ C,
                                                int M, int N, int K)
{
    constexpr int RM = BM / 32, RN = BN / 32;
    constexpr int ITA = BM / 32, ITB = BN / 32;   // gload16 per thread per tile
    __shared__ unsigned short As[2][BM * 64];
    __shared__ unsigned short Bs[2][BN * 64];

    int tid  = threadIdx.x;
    int lane = tid & 63, wave = tid >> 6;
    int wr = wave >> 1, wc = wave & 1;
    int bm = blockIdx.y * BM, bn = blockIdx.x * BN;
    int l15 = lane & 15, lk = lane >> 4;

    const bf16* gA[ITA]; const bf16* gB[ITB];
    #pragma unroll
    for (int it = 0; it < ITA; ++it) {
        int e = it * 256 + tid, row = e >> 3, g = e & 7;
        gA[it] = &A[(size_t)(bm + row) * K + (g ^ (row & 7)) * 8];
    }
    #pragma unroll
    for (int it = 0; it < ITB; ++it) {
        int e = it * 256 + tid, row = e >> 3, g = e & 7;
        gB[it] = &Bt[(size_t)(bn + row) * K + (g ^ (row & 7)) * 8];
    }

    f32x4 acc[RM][RN] = {};
    int NT = K >> 6;

    #pragma unroll
    for (int it = 0; it < ITA; ++it) gload16(gA[it], &As[0][(it * 256 + tid) * 8]);
    #pragma unroll
    for (int it = 0; it < ITB; ++it) gload16(gB[it], &Bs[0][(it * 256 + tid) * 8]);
    __syncthreads();

    for (int t = 0; t < NT; ++t) {
        int cur = t & 1;
        if (t + 1 < NT) {
            #pragma unroll
            for (int it = 0; it < ITA; ++it)
                gload16(gA[it] + (t + 1) * 64, &As[cur ^ 1][(it * 256 + tid) * 8]);
            #pragma unroll
            for (int it = 0; it < ITB; ++it)
                gload16(gB[it] + (t + 1) * 64, &Bs[cur ^ 1][(it * 256 + tid) * 8]);
        }
        #pragma unroll
        for (int s = 0; s < 2; ++s) {
            bf16x8 a[RM], b[RN];
            int g8 = ((s * 4 + lk) ^ (l15 & 7)) * 8;
            #pragma unroll
            for (int m = 0; m < RM; ++m) {
                int row = wr * (BM / 2) + m * 16 + l15;
                a[m] = *(const bf16x8*)&As[cur][row * 64 + g8];
            }
            #pragma unroll
            for (int n = 0; n < RN; ++n) {
                int row = wc * (BN / 2) + n * 16 + l15;
                b[n] = *(const bf16x8*)&Bs[cur][row * 64 + g8];
            }
            #pragma unroll
            for (int m = 0; m < RM; ++m)
                #pragma unroll
                for (int n = 0; n < RN; ++n)
                    acc[m][n] = __builtin_amdgcn_mfma_f32_16x16x32_bf16(a[m], b[n], acc[m][n], 0, 0, 0);
        }
        __syncthreads();
    }

    #pragma unroll
    for (int m = 0; m < RM; ++m) {
        #pragma unroll
        for (int n = 0; n < RN; ++n) {
            int gcol = bn + wc * (BN / 2) + n * 16 + l15;
            float bs = bias[gcol];
            #pragma unroll
            for (int r = 0; r < 4; ++r) {
                int grow = bm + wr * (BM / 2) + m * 16 + lk * 4 + r;
                float x = acc[m][n][r];
                float o;
                if constexpr (EPI == 2) {
                    o = x + bs + res[(size_t)grow * N + gcol];
                } else if constexpr (EPI == 3) {
                    float t = x + bs;
                    float u = t + 0.044715f * t * t * t;
                    o = 0.5f * t * (1.0f + tanhf(0.7978845608028654f * u));
                } else {
                    o = x + bs + res[(size_t)grow * N + gcol];
                }
                stc(C, (size_t)grow * N + gcol, o);
            }
        }
    }
}

// ----- fused Q+V GEMM (128x128 tile): Bt = [QwT;VwT] (1024x512) -----
// Q tiles (bn<512): per-wave head = (bn>>6)+wc; sigmoid-gate row-sums -> qs.
// V tiles: x + Vb -> vbuf.
__global__ __launch_bounds__(256) void gemm_qv(const bf16* __restrict__ A,
                                               const bf16* __restrict__ Bt,
                                               const float* __restrict__ qb,
                                               const float* __restrict__ Vb,
                                               float* __restrict__ qs,
                                               float* __restrict__ vbuf)
{
    constexpr int BM = 128, BN = 128, RM = 4, RN = 4;
    __shared__ unsigned short As[2][BM * 64];
    __shared__ unsigned short Bs[2][BN * 64];
    __shared__ float qsums[2][128];

    const int K = DIM;
    int tid  = threadIdx.x;
    int lane = tid & 63, wave = tid >> 6;
    int wr = wave >> 1, wc = wave & 1;
    int bm = blockIdx.y * BM, bn = blockIdx.x * BN;
    int l15 = lane & 15, lk = lane >> 4;

    const bf16* gA[4]; const bf16* gB[4];
    #pragma unroll
    for (int it = 0; it < 4; ++it) {
        int e = it * 256 + tid, row = e >> 3, g = e & 7;
        int kc = (g ^ (row & 7)) * 8;
        gA[it] = &A [(size_t)(bm + row) * K + kc];
        gB[it] = &Bt[(size_t)(bn + row) * K + kc];
    }

    f32x4 acc[RM][RN] = {};
    const int NT = K >> 6;   // 8

    #pragma unroll
    for (int it = 0; it < 4; ++it) {
        gload16(gA[it], &As[0][(it * 256 + tid) * 8]);
        gload16(gB[it], &Bs[0][(it * 256 + tid) * 8]);
    }
    __syncthreads();

    for (int t = 0; t < NT; ++t) {
        int cur = t & 1;
        if (t + 1 < NT) {
            #pragma unroll
            for (int it = 0; it < 4; ++it) {
                gload16(gA[it] + (t + 1) * 64, &As[cur ^ 1][(it * 256 + tid) * 8]);
                gload16(gB[it] + (t + 1) * 64, &Bs[cur ^ 1][(it * 256 + tid) * 8]);
            }
        }
        #pragma unroll
        for (int s = 0; s < 2; ++s) {
            bf16x8 a[RM], b[RN];
            int g8 = ((s * 4 + lk) ^ (l15 & 7)) * 8;
            #pragma unroll
            for (int m = 0; m < RM; ++m) {
                int row = wr * 64 + m * 16 + l15;
                a[m] = *(const bf16x8*)&As[cur][row * 64 + g8];
            }
            #pragma unroll
            for (int n = 0; n < RN; ++n) {
                int row = wc * 64 + n * 16 + l15;
                b[n] = *(const bf16x8*)&Bs[cur][row * 64 + g8];
            }
            #pragma unroll
            for (int m = 0; m < RM; ++m)
                #pragma unroll
                for (int n = 0; n < RN; ++n)
                    acc[m][n] = __builtin_amdgcn_mfma_f32_16x16x32_bf16(a[m], b[n], acc[m][n], 0, 0, 0);
        }
        __syncthreads();
    }

    if (bn < DIM) {
        // Q gate: sigmoid(x - exp(qb))/64, summed over this wave's head (64 cols)
        float eq[RN];
        #pragma unroll
        for (int n = 0; n < RN; ++n)
            eq[n] = expf(qb[bn + wc * 64 + n * 16 + l15]);
        #pragma unroll
        for (int m = 0; m < RM; ++m) {
            #pragma unroll
            for (int r = 0; r < 4; ++r) {
                float s = 0.f;
                #pragma unroll
                for (int n = 0; n < RN; ++n) {
                    float x = acc[m][n][r] - eq[n];
                    s += 1.0f / (1.0f + expf(-x));
                }
                s *= (1.0f / 64.0f);
                #pragma unroll
                for (int off = 1; off < 16; off <<= 1) s += __shfl_xor(s, off);
                if (l15 == 0)
                    qsums[wc][wr * 64 + m * 16 + lk * 4 + r] = s;
            }
        }
        __syncthreads();
        int hh = tid >> 7, row = tid & 127;
        qs[(size_t)(bm + row) * NH + (bn >> 6) + hh] = qsums[hh][row];
    } else {
        #pragma unroll
        for (int m = 0; m < RM; ++m) {
            #pragma unroll
            for (int n = 0; n < RN; ++n) {
                int gcol = bn - DIM + wc * 64 + n * 16 + l15;
                float bs = Vb[gcol];
                #pragma unroll
                for (int r = 0; r < 4; ++r) {
                    int grow = bm + wr * 64 + m * 16 + lk * 4 + r;
                    vbuf[(size_t)grow * DIM + gcol] = acc[m][n][r] + bs;
                }
            }
        }
    }
}

// ---- W^T partials: WT[bh][hd][d] = sum_t v[b,t,h,hd] * time[t,h,d] --------
__global__ __launch_bounds__(256) void wpart_kernel(const float* __restrict__ v,
                                                    const bf16* __restrict__ timef,
                                                    float* __restrict__ wpart)
{
    int bh = blockIdx.x;          // 0..15
    int kc = blockIdx.y;          // 0..KCH-1
    int b = bh >> 3, h = bh & 7;
    int hd = threadIdx.x & 63, dg = threadIdx.x >> 6;

    float acc[32] = {};
    int t0 = kc * TCH;
    #pragma unroll 4
    for (int t = t0; t < t0 + TCH; ++t) {
        float vv = v[((size_t)(b * LSEQ + t)) * DIM + h * HDIM + hd];
        const bf16* tp = timef + ((size_t)t * NH + h) * TF + dg * 32;
        bf16x8 tv[4];
        #pragma unroll
        for (int q = 0; q < 4; ++q) tv[q] = *(const bf16x8*)&tp[q * 8];
        #pragma unroll
        for (int q = 0; q < 4; ++q)
            #pragma unroll
            for (int j = 0; j < 8; ++j)
                acc[q * 8 + j] = fmaf((float)tv[q][j], vv, acc[q * 8 + j]);
    }
    float* wp = wpart + ((size_t)(kc * 16 + bh)) * (TF * HDIM) + (size_t)hd * TF + dg * 32;
    #pragma unroll
    for (int q = 0; q < 8; ++q) {
        float4 o = {acc[q * 4], acc[q * 4 + 1], acc[q * 4 + 2], acc[q * 4 + 3]};
        ((float4*)wp)[q] = o;
    }
}

__global__ __launch_bounds__(256) void wred_kernel(const float* __restrict__ wpart,
                                                   bf16* __restrict__ WT)
{
    int i = blockIdx.x * 256 + threadIdx.x;   // < 131072
    float s = 0.f;
    #pragma unroll
    for (int kc = 0; kc < KCH; ++kc)
        s += wpart[(size_t)kc * 131072 + i];
    WT[i] = __float2bfloat16(s);
}

// ---- comb[b,l,h,:] = qs[l,h]*mask[l] * (time[l,h,:] @ WT[bh]^T), MFMA ------
__global__ __launch_bounds__(256) void comb_mfma(const bf16* __restrict__ timef,
                                                 const bf16* __restrict__ WT,
                                                 const float* __restrict__ qs,
                                                 const float* __restrict__ mask,
                                                 bf16* __restrict__ comb)
{
    int bh = blockIdx.x;
    int b = bh >> 3, h = bh & 7;
    int lane = threadIdx.x & 63, wave = threadIdx.x >> 6;
    int l15 = lane & 15, lk = lane >> 4;
    int lbase = blockIdx.y * 256 + wave * 64;

    const bf16* wt = WT + (size_t)bh * (HDIM * TF);

    f32x4 acc[4][4] = {};
    #pragma unroll
    for (int ks = 0; ks < 4; ++ks) {
        int kt = ks * 32;
        bf16x8 a[4], bf[4];
        #pragma unroll
        for (int m = 0; m < 4; ++m) {
            int l = lbase + m * 16 + l15;
            a[m] = *(const bf16x8*)&timef[((size_t)l * NH + h) * TF + kt + lk * 8];
        }
        #pragma unroll
        for (int n = 0; n < 4; ++n)
            bf[n] = *(const bf16x8*)&wt[(size_t)(n * 16 + l15) * TF + kt + lk * 8];
        #pragma unroll
        for (int m = 0; m < 4; ++m)
            #pragma unroll
            for (int n = 0; n < 4; ++n)
                acc[m][n] = __builtin_amdgcn_mfma_f32_16x16x32_bf16(a[m], bf[n], acc[m][n], 0, 0, 0);
    }

    #pragma unroll
    for (int m = 0; m < 4; ++m) {
        #pragma unroll
        for (int r = 0; r < 4; ++r) {
            int l = lbase + m * 16 + lk * 4 + r;
            int row = b * LSEQ + l;
            float q = qs[(size_t)row * NH + h] * mask[row];
            #pragma unroll
            for (int n = 0; n < 4; ++n) {
                int hd = n * 16 + l15;
                comb[(size_t)row * DIM + h * HDIM + hd] =
                    __float2bfloat16(q * acc[m][n][r]);
            }
        }
    }
}

// ---------------- LayerNorm over last dim (512) ----------------
template<int WB>
__global__ __launch_bounds__(256) void ln_kernel(const float* __restrict__ X,
                                                 const float* __restrict__ g,
                                                 const float* __restrict__ bta,
                                                 float* __restrict__ outf,
                                                 bf16* __restrict__ outb)
{
    int row = blockIdx.x;
    const float* x = X + (size_t)row * DIM;
    float v0 = x[threadIdx.x], v1 = x[threadIdx.x + 256];
    float s = v0 + v1, s2 = v0 * v0 + v1 * v1;
    #pragma unroll
    for (int off = 1; off < 64; off <<= 1) {
        s  += __shfl_xor(s,  off);
        s2 += __shfl_xor(s2, off);
    }
    __shared__ float sh[2][4];
    int wave = threadIdx.x >> 6, lane = threadIdx.x & 63;
    if (lane == 0) { sh[0][wave] = s; sh[1][wave] = s2; }
    __syncthreads();
    s  = sh[0][0] + sh[0][1] + sh[0][2] + sh[0][3];
    s2 = sh[1][0] + sh[1][1] + sh[1][2] + sh[1][3];
    float mu  = s * (1.0f / DIM);
    float var = s2 * (1.0f / DIM) - mu * mu;
    float inv = rsqrtf(var + 1e-5f);
    int c0 = threadIdx.x, c1 = threadIdx.x + 256;
    float o0 = (v0 - mu) * inv * g[c0] + bta[c0];
    float o1 = (v1 - mu) * inv * g[c1] + bta[c1];
    outf[(size_t)row * DIM + c0] = o0;
    outf[(size_t)row * DIM + c1] = o1;
    if constexpr (WB) {
        outb[(size_t)row * DIM + c0] = __float2bfloat16(o0);
        outb[(size_t)row * DIM + c1] = __float2bfloat16(o1);
    }
}

extern "C" void kernel_launch(void* const* d_in, const int* in_sizes, int n_in,
                              void* d_out, int out_size, void* d_ws, size_t ws_size,
                              hipStream_t stream)
{
    const float* tensor = (const float*)d_in[0];
    const float* mask   = (const float*)d_in[1];
    const float* tang   = (const float*)d_in[2];
    const float* htd    = (const float*)d_in[3];
    const float* Qw     = (const float*)d_in[4];
    const float* qb     = (const float*)d_in[5];
    // d_in[6], d_in[7] (Kw, Kb) dead code
    const float* Vw     = (const float*)d_in[8];
    const float* Vb     = (const float*)d_in[9];
    const float* Ow     = (const float*)d_in[10];
    const float* Ob     = (const float*)d_in[11];
    const float* g1     = (const float*)d_in[12];
    const float* b1     = (const float*)d_in[13];
    const float* Win    = (const float*)d_in[14];
    const float* bin    = (const float*)d_in[15];
    const float* Wout   = (const float*)d_in[16];
    const float* bout   = (const float*)d_in[17];
    const float* g2     = (const float*)d_in[18];
    const float* b2     = (const float*)d_in[19];
    float* out = (float*)d_out;

    float* ws = (float*)d_ws;
    // f32-unit offsets. Lifetimes (written -> last read), identical to round 8:
    //   vbuf    [0,        2097152)  v: s2->s3;   preLN1: s6->s7
    //   actb    [0,        3145728)  bf16 FFN act: s8->s9
    //   tensorb [2097152,  3145728)  s1->s2; combb reuse: s5->s6
    //   timefb  [3145728,  4194304)  s1->s5
    //   interb  [4194304,  5242880)  s7->s8
    //   wpart   [5242880,  9437184)  s3->s4  (32 x 131072)
    //   buf5    [5242880,  7340032)  preLN2: s9->s10
    //   inter   [7340032,  9437184)  f32: s7->s9
    //   WTb     [9437184,  9502720)  bf16: s4->s5
    //   qs      [9502720,  9535488)  f32:  s2->s5
    //   QVwT    [9535488,  9797632)  bf16 [1024][512]: s1->s2
    //   OwT     [9797632,  9928704)  s1->s6
    //   WinT    [9928704, 10321920)  s1->s8
    //   WoutT   [10321920,10715136)  s1->s9
    // peak = 10715136 f32 = 42.9 MB
    float* vbuf   = ws + 0;
    bf16*  actb   = (bf16*)(ws + 0);
    bf16*  tensorb= (bf16*)(ws + 2097152);
    bf16*  combb  = tensorb;
    bf16*  timefb = (bf16*)(ws + 3145728);
    bf16*  interb = (bf16*)(ws + 4194304);
    float* wpart  = ws + 5242880;
    float* buf5   = ws + 5242880;
    float* inter  = ws + 7340032;
    bf16*  WTb    = (bf16*)(ws + 9437184);
    float* qs     = ws + 9502720;
    bf16*  QVwT   = (bf16*)(ws + 9535488);
    bf16*  QwT    = QVwT;                         // rows 0..511
    bf16*  VwT    = QVwT + (size_t)512 * 512;     // rows 512..1023
    bf16*  OwT    = (bf16*)(ws + 9797632);
    bf16*  WinT   = (bf16*)(ws + 9928704);
    bf16*  WoutT  = (bf16*)(ws + 10321920);

    // 1. setup: tensor->bf16 + time features + weight transposes
    setup_kernel<<<8448, 256, 0, stream>>>(tensor, tang, htd, Qw, Vw, Ow, Win, Wout,
                                           tensorb, timefb, QwT, VwT, OwT, WinT, WoutT);
    // 2. fused Q+V GEMM (128x128): qs row-sums + vbuf
    gemm_qv<<<dim3(8, 32), 256, 0, stream>>>(tensorb, QVwT, qb, Vb, qs, vbuf);
    // 3. WT partials (split-K 32)
    wpart_kernel<<<dim3(16, KCH), 256, 0, stream>>>(vbuf, timefb, wpart);
    // 4. reduce -> WT bf16
    wred_kernel<<<512, 256, 0, stream>>>(wpart, WTb);
    // 5. comb via MFMA
    comb_mfma<<<dim3(16, 8), 256, 0, stream>>>(timefb, WTb, qs, mask, combb);
    // 6. attn_out + residual(tensor) -> preLN1  (64x128 tile)
    gemm_big<64, 128, 2, float><<<dim3(4, 64), 256, 0, stream>>>(combb, OwT, Ob, tensor, vbuf, ROWS, DIM, DIM);
    // 7. LN1 -> inter f32 + interb bf16
    ln_kernel<1><<<ROWS, 256, 0, stream>>>(vbuf, g1, b1, inter, interb);
    // 8. FFN in + gelu -> bf16  (128x128 tile)
    gemm_big<128, 128, 3, bf16><<<dim3(12, 32), 256, 0, stream>>>(interb, WinT, bin, nullptr, actb, ROWS, LIND, DIM);
    // 9. FFN out + residual(inter)  (64x128 tile)
    gemm_big<64, 128, 4, float><<<dim3(4, 64), 256, 0, stream>>>(actb, WoutT, bout, inter, buf5, ROWS, DIM, LIND);
    // 10. LN2 -> f32 output
    ln_kernel<0><<<ROWS, 256, 0, stream>>>(buf5, g2, b2, out, nullptr);
}

// Round 10
// 123.155 us; speedup vs baseline: 1.1440x; 1.1440x over previous
//
#include <hip/hip_runtime.h>
#include <hip/hip_bf16.h>

typedef __hip_bfloat16 bf16;
typedef __attribute__((ext_vector_type(8))) __bf16 bf16x8;
typedef __attribute__((ext_vector_type(4))) float f32x4;

#define DIM   512
#define NH    8
#define HDIM  64
#define LIND  1536
#define LSEQ  2048
#define ROWS  4096        // B*L
#define TF    128         // time features
#define KCH   32          // wpart split-K chunks
#define TCH   64          // t per chunk

__device__ __forceinline__ float b2f(bf16 v){ return __bfloat162float(v); }
__device__ __forceinline__ void stc(float* C, size_t i, float v){ C[i] = v; }
__device__ __forceinline__ void stc(bf16*  C, size_t i, float v){ C[i] = __float2bfloat16(v); }

typedef const __attribute__((address_space(1))) unsigned int* gp1_t;
typedef __attribute__((address_space(3))) unsigned int* lp3_t;
__device__ __forceinline__ void gload16(const bf16* g, unsigned short* l) {
    __builtin_amdgcn_global_load_lds((gp1_t)(const void*)g, (lp3_t)(void*)l, 16, 0, 0);
}

// ---------- setup: tensor->bf16 | time features | 5 weight transposes ----------
__global__ __launch_bounds__(256) void setup_kernel(const float* __restrict__ tensor,
                                                    const float* __restrict__ tang,
                                                    const float* __restrict__ htd,
                                                    const float* __restrict__ Qw,
                                                    const float* __restrict__ Vw,
                                                    const float* __restrict__ Ow,
                                                    const float* __restrict__ Win,
                                                    const float* __restrict__ Wout,
                                                    bf16* __restrict__ tensorb,
                                                    bf16* __restrict__ timef,
                                                    bf16* __restrict__ QwT,
                                                    bf16* __restrict__ VwT,
                                                    bf16* __restrict__ OwT,
                                                    bf16* __restrict__ WinT,
                                                    bf16* __restrict__ WoutT)
{
    int id = blockIdx.x;
    if (id < 2048) {
        int i = id * 256 + threadIdx.x;
        float4 v = ((const float4*)tensor)[i];
        bf16 t[4];
        t[0] = __float2bfloat16(v.x); t[1] = __float2bfloat16(v.y);
        t[2] = __float2bfloat16(v.z); t[3] = __float2bfloat16(v.w);
        *(uint2*)&tensorb[(size_t)i * 4] = *(uint2*)t;
        return;
    }
    if (id < 6144) {
        int idx = (id - 2048) * 256 + threadIdx.x;   // < 1048576
        int d = idx & 63;
        int h = (idx >> 6) & 7;
        int l = idx >> 9;
        float ang = ((float)l + htd[h]) * tang[h * 64 + d];
        float s, c;
        sincosf(ang, &s, &c);
        bf16* p = timef + ((size_t)l * NH + h) * TF;
        p[d]      = __float2bfloat16((c + s) * 0.125f);
        p[d + 64] = __float2bfloat16((c - s) * 0.125f);
        return;
    }
    id -= 6144;
    const float* in; bf16* out; int R, C, tx, ty;
    if (id < 256)        { in = Qw;   out = QwT;   R = 512;  C = 512;  tx = id & 15; ty = id >> 4; }
    else if (id < 512)   { id -= 256;  in = Vw;   out = VwT;   R = 512;  C = 512;  tx = id & 15; ty = id >> 4; }
    else if (id < 768)   { id -= 512;  in = Ow;   out = OwT;   R = 512;  C = 512;  tx = id & 15; ty = id >> 4; }
    else if (id < 1536)  { id -= 768;  in = Win;  out = WinT;  R = 512;  C = 1536; tx = id % 48; ty = id / 48; }
    else                 { id -= 1536; in = Wout; out = WoutT; R = 1536; C = 512;  tx = id & 15; ty = id >> 4; }

    __shared__ float t[32][33];
    int bx = tx * 32, by = ty * 32;
    int x = threadIdx.x & 31, y = threadIdx.x >> 5;
    #pragma unroll
    for (int r = 0; r < 32; r += 8)
        t[y + r][x] = in[(size_t)(by + y + r) * C + bx + x];
    __syncthreads();
    #pragma unroll
    for (int r = 0; r < 32; r += 8)
        out[(size_t)(bx + y + r) * R + by + x] = __float2bfloat16(t[x][y + r]);
}

// ===== BK=64 double-buffered MFMA GEMM (both-sides XOR swizzle) =====
// LDS tile [rows][64 k]; staging slot e: row=e>>3, granule g=e&7 holds global
// granule g^(row&7); reads XOR identically -> conflict-free (2-way alias only).
// 4 waves 2x2; wave tile (BM/2)x(BN/2); RM=BM/32, RN=BN/32 frags.

// ---------------- generic GEMM: C = epi(A[M,K] @ Bt[N,K]^T) ----------------
// EPI: 2 = x+b+res (O)   3 = gelu(x+b) (FFN1)   4 = x+b+res (FFN2)
template<int BM, int BN, int EPI, typename OUTT>
__global__ __launch_bounds__(256) void gemm_big(const bf16* __restrict__ A,
                                                const bf16* __restrict__ Bt,
                                                const float* __restrict__ bias,
                                                const float* __restrict__ res,
                                                OUTT* __restrict__ C,
                                                int M, int N, int K)
{
    constexpr int RM = BM / 32, RN = BN / 32;
    constexpr int ITA = BM / 32, ITB = BN / 32;
    __shared__ unsigned short As[2][BM * 64];
    __shared__ unsigned short Bs[2][BN * 64];

    int tid  = threadIdx.x;
    int lane = tid & 63, wave = tid >> 6;
    int wr = wave >> 1, wc = wave & 1;
    int bm = blockIdx.y * BM, bn = blockIdx.x * BN;
    int l15 = lane & 15, lk = lane >> 4;

    const bf16* gA[ITA]; const bf16* gB[ITB];
    #pragma unroll
    for (int it = 0; it < ITA; ++it) {
        int e = it * 256 + tid, row = e >> 3, g = e & 7;
        gA[it] = &A[(size_t)(bm + row) * K + (g ^ (row & 7)) * 8];
    }
    #pragma unroll
    for (int it = 0; it < ITB; ++it) {
        int e = it * 256 + tid, row = e >> 3, g = e & 7;
        gB[it] = &Bt[(size_t)(bn + row) * K + (g ^ (row & 7)) * 8];
    }

    f32x4 acc[RM][RN] = {};
    int NT = K >> 6;

    #pragma unroll
    for (int it = 0; it < ITA; ++it) gload16(gA[it], &As[0][(it * 256 + tid) * 8]);
    #pragma unroll
    for (int it = 0; it < ITB; ++it) gload16(gB[it], &Bs[0][(it * 256 + tid) * 8]);
    __syncthreads();

    for (int t = 0; t < NT; ++t) {
        int cur = t & 1;
        if (t + 1 < NT) {
            #pragma unroll
            for (int it = 0; it < ITA; ++it)
                gload16(gA[it] + (t + 1) * 64, &As[cur ^ 1][(it * 256 + tid) * 8]);
            #pragma unroll
            for (int it = 0; it < ITB; ++it)
                gload16(gB[it] + (t + 1) * 64, &Bs[cur ^ 1][(it * 256 + tid) * 8]);
        }
        #pragma unroll
        for (int s = 0; s < 2; ++s) {
            bf16x8 a[RM], b[RN];
            int g8 = ((s * 4 + lk) ^ (l15 & 7)) * 8;
            #pragma unroll
            for (int m = 0; m < RM; ++m) {
                int row = wr * (BM / 2) + m * 16 + l15;
                a[m] = *(const bf16x8*)&As[cur][row * 64 + g8];
            }
            #pragma unroll
            for (int n = 0; n < RN; ++n) {
                int row = wc * (BN / 2) + n * 16 + l15;
                b[n] = *(const bf16x8*)&Bs[cur][row * 64 + g8];
            }
            #pragma unroll
            for (int m = 0; m < RM; ++m)
                #pragma unroll
                for (int n = 0; n < RN; ++n)
                    acc[m][n] = __builtin_amdgcn_mfma_f32_16x16x32_bf16(a[m], b[n], acc[m][n], 0, 0, 0);
        }
        __syncthreads();
    }

    #pragma unroll
    for (int m = 0; m < RM; ++m) {
        #pragma unroll
        for (int n = 0; n < RN; ++n) {
            int gcol = bn + wc * (BN / 2) + n * 16 + l15;
            float bs = bias[gcol];
            #pragma unroll
            for (int r = 0; r < 4; ++r) {
                int grow = bm + wr * (BM / 2) + m * 16 + lk * 4 + r;
                float x = acc[m][n][r];
                float o;
                if constexpr (EPI == 2) {
                    o = x + bs + res[(size_t)grow * N + gcol];
                } else if constexpr (EPI == 3) {
                    float t = x + bs;
                    float u = t + 0.044715f * t * t * t;
                    o = 0.5f * t * (1.0f + tanhf(0.7978845608028654f * u));
                } else {
                    o = x + bs + res[(size_t)grow * N + gcol];
                }
                stc(C, (size_t)grow * N + gcol, o);
            }
        }
    }
}

// ----- fused Q+V GEMM, BM=64 BN=128: Bt = [QwT;VwT] (1024x512) -----
// Q tiles (bn<512): wave-column wc owns one head (64 cols); sigmoid-gate
// row-sums -> qs. V tiles: x + Vb -> vbuf.
__global__ __launch_bounds__(256) void gemm_qv(const bf16* __restrict__ A,
                                               const bf16* __restrict__ Bt,
                                               const float* __restrict__ qb,
                                               const float* __restrict__ Vb,
                                               float* __restrict__ qs,
                                               float* __restrict__ vbuf)
{
    constexpr int BM = 64, BN = 128, RM = 2, RN = 4;
    __shared__ unsigned short As[2][BM * 64];
    __shared__ unsigned short Bs[2][BN * 64];
    __shared__ float qsums[2][64];

    const int K = DIM;
    int tid  = threadIdx.x;
    int lane = tid & 63, wave = tid >> 6;
    int wr = wave >> 1, wc = wave & 1;
    int bm = blockIdx.y * BM, bn = blockIdx.x * BN;
    int l15 = lane & 15, lk = lane >> 4;

    const bf16* gA[2]; const bf16* gB[4];
    #pragma unroll
    for (int it = 0; it < 2; ++it) {
        int e = it * 256 + tid, row = e >> 3, g = e & 7;
        gA[it] = &A[(size_t)(bm + row) * K + (g ^ (row & 7)) * 8];
    }
    #pragma unroll
    for (int it = 0; it < 4; ++it) {
        int e = it * 256 + tid, row = e >> 3, g = e & 7;
        gB[it] = &Bt[(size_t)(bn + row) * K + (g ^ (row & 7)) * 8];
    }

    f32x4 acc[RM][RN] = {};
    const int NT = K >> 6;   // 8

    #pragma unroll
    for (int it = 0; it < 2; ++it) gload16(gA[it], &As[0][(it * 256 + tid) * 8]);
    #pragma unroll
    for (int it = 0; it < 4; ++it) gload16(gB[it], &Bs[0][(it * 256 + tid) * 8]);
    __syncthreads();

    for (int t = 0; t < NT; ++t) {
        int cur = t & 1;
        if (t + 1 < NT) {
            #pragma unroll
            for (int it = 0; it < 2; ++it)
                gload16(gA[it] + (t + 1) * 64, &As[cur ^ 1][(it * 256 + tid) * 8]);
            #pragma unroll
            for (int it = 0; it < 4; ++it)
                gload16(gB[it] + (t + 1) * 64, &Bs[cur ^ 1][(it * 256 + tid) * 8]);
        }
        #pragma unroll
        for (int s = 0; s < 2; ++s) {
            bf16x8 a[RM], b[RN];
            int g8 = ((s * 4 + lk) ^ (l15 & 7)) * 8;
            #pragma unroll
            for (int m = 0; m < RM; ++m) {
                int row = wr * 32 + m * 16 + l15;
                a[m] = *(const bf16x8*)&As[cur][row * 64 + g8];
            }
            #pragma unroll
            for (int n = 0; n < RN; ++n) {
                int row = wc * 64 + n * 16 + l15;
                b[n] = *(const bf16x8*)&Bs[cur][row * 64 + g8];
            }
            #pragma unroll
            for (int m = 0; m < RM; ++m)
                #pragma unroll
                for (int n = 0; n < RN; ++n)
                    acc[m][n] = __builtin_amdgcn_mfma_f32_16x16x32_bf16(a[m], b[n], acc[m][n], 0, 0, 0);
        }
        __syncthreads();
    }

    if (bn < DIM) {
        // Q gate: sigmoid(x - exp(qb))/64, summed over this wave's head (64 cols)
        float eq[RN];
        #pragma unroll
        for (int n = 0; n < RN; ++n)
            eq[n] = expf(qb[bn + wc * 64 + n * 16 + l15]);
        #pragma unroll
        for (int m = 0; m < RM; ++m) {
            #pragma unroll
            for (int r = 0; r < 4; ++r) {
                float s = 0.f;
                #pragma unroll
                for (int n = 0; n < RN; ++n) {
                    float x = acc[m][n][r] - eq[n];
                    s += 1.0f / (1.0f + expf(-x));
                }
                s *= (1.0f / 64.0f);
                #pragma unroll
                for (int off = 1; off < 16; off <<= 1) s += __shfl_xor(s, off);
                if (l15 == 0)
                    qsums[wc][wr * 32 + m * 16 + lk * 4 + r] = s;
            }
        }
        __syncthreads();
        if (tid < 128) {
            int hh = tid >> 6, row = tid & 63;
            qs[(size_t)(bm + row) * NH + (bn >> 6) + hh] = qsums[hh][row];
        }
    } else {
        #pragma unroll
        for (int m = 0; m < RM; ++m) {
            #pragma unroll
            for (int n = 0; n < RN; ++n) {
                int gcol = bn - DIM + wc * 64 + n * 16 + l15;
                float bs = Vb[gcol];
                #pragma unroll
                for (int r = 0; r < 4; ++r) {
                    int grow = bm + wr * 32 + m * 16 + lk * 4 + r;
                    vbuf[(size_t)grow * DIM + gcol] = acc[m][n][r] + bs;
                }
            }
        }
    }
}

// ---- W^T partials: WT[bh][hd][d] = sum_t v[b,t,h,hd] * time[t,h,d] --------
__global__ __launch_bounds__(256) void wpart_kernel(const float* __restrict__ v,
                                                    const bf16* __restrict__ timef,
                                                    float* __restrict__ wpart)
{
    int bh = blockIdx.x;          // 0..15
    int kc = blockIdx.y;          // 0..KCH-1
    int b = bh >> 3, h = bh & 7;
    int hd = threadIdx.x & 63, dg = threadIdx.x >> 6;

    float acc[32] = {};
    int t0 = kc * TCH;
    #pragma unroll 4
    for (int t = t0; t < t0 + TCH; ++t) {
        float vv = v[((size_t)(b * LSEQ + t)) * DIM + h * HDIM + hd];
        const bf16* tp = timef + ((size_t)t * NH + h) * TF + dg * 32;
        bf16x8 tv[4];
        #pragma unroll
        for (int q = 0; q < 4; ++q) tv[q] = *(const bf16x8*)&tp[q * 8];
        #pragma unroll
        for (int q = 0; q < 4; ++q)
            #pragma unroll
            for (int j = 0; j < 8; ++j)
                acc[q * 8 + j] = fmaf((float)tv[q][j], vv, acc[q * 8 + j]);
    }
    float* wp = wpart + ((size_t)(kc * 16 + bh)) * (TF * HDIM) + (size_t)hd * TF + dg * 32;
    #pragma unroll
    for (int q = 0; q < 8; ++q) {
        float4 o = {acc[q * 4], acc[q * 4 + 1], acc[q * 4 + 2], acc[q * 4 + 3]};
        ((float4*)wp)[q] = o;
    }
}

__global__ __launch_bounds__(256) void wred_kernel(const float* __restrict__ wpart,
                                                   bf16* __restrict__ WT)
{
    int i = blockIdx.x * 256 + threadIdx.x;   // < 131072
    float s = 0.f;
    #pragma unroll
    for (int kc = 0; kc < KCH; ++kc)
        s += wpart[(size_t)kc * 131072 + i];
    WT[i] = __float2bfloat16(s);
}

// ---- comb[b,l,h,:] = qs[l,h]*mask[l] * (time[l,h,:] @ WT[bh]^T), MFMA ------
// grid (16,16); 4 waves x 32 l-rows each; 256 blocks = 1/CU
__global__ __launch_bounds__(256) void comb_mfma(const bf16* __restrict__ timef,
                                                 const bf16* __restrict__ WT,
                                                 const float* __restrict__ qs,
                                                 const float* __restrict__ mask,
                                                 bf16* __restrict__ comb)
{
    int bh = blockIdx.x;
    int b = bh >> 3, h = bh & 7;
    int lane = threadIdx.x & 63, wave = threadIdx.x >> 6;
    int l15 = lane & 15, lk = lane >> 4;
    int lbase = blockIdx.y * 128 + wave * 32;

    const bf16* wt = WT + (size_t)bh * (HDIM * TF);

    f32x4 acc[2][4] = {};
    #pragma unroll
    for (int ks = 0; ks < 4; ++ks) {
        int kt = ks * 32;
        bf16x8 a[2], bf[4];
        #pragma unroll
        for (int m = 0; m < 2; ++m) {
            int l = lbase + m * 16 + l15;
            a[m] = *(const bf16x8*)&timef[((size_t)l * NH + h) * TF + kt + lk * 8];
        }
        #pragma unroll
        for (int n = 0; n < 4; ++n)
            bf[n] = *(const bf16x8*)&wt[(size_t)(n * 16 + l15) * TF + kt + lk * 8];
        #pragma unroll
        for (int m = 0; m < 2; ++m)
            #pragma unroll
            for (int n = 0; n < 4; ++n)
                acc[m][n] = __builtin_amdgcn_mfma_f32_16x16x32_bf16(a[m], bf[n], acc[m][n], 0, 0, 0);
    }

    #pragma unroll
    for (int m = 0; m < 2; ++m) {
        #pragma unroll
        for (int r = 0; r < 4; ++r) {
            int l = lbase + m * 16 + lk * 4 + r;
            int row = b * LSEQ + l;
            float q = qs[(size_t)row * NH + h] * mask[row];
            #pragma unroll
            for (int n = 0; n < 4; ++n) {
                int hd = n * 16 + l15;
                comb[(size_t)row * DIM + h * HDIM + hd] =
                    __float2bfloat16(q * acc[m][n][r]);
            }
        }
    }
}

// ---------------- LayerNorm over last dim (512) ----------------
template<int WB>
__global__ __launch_bounds__(256) void ln_kernel(const float* __restrict__ X,
                                                 const float* __restrict__ g,
                                                 const float* __restrict__ bta,
                                                 float* __restrict__ outf,
                                                 bf16* __restrict__ outb)
{
    int row = blockIdx.x;
    const float* x = X + (size_t)row * DIM;
    float v0 = x[threadIdx.x], v1 = x[threadIdx.x + 256];
    float s = v0 + v1, s2 = v0 * v0 + v1 * v1;
    #pragma unroll
    for (int off = 1; off < 64; off <<= 1) {
        s  += __shfl_xor(s,  off);
        s2 += __shfl_xor(s2, off);
    }
    __shared__ float sh[2][4];
    int wave = threadIdx.x >> 6, lane = threadIdx.x & 63;
    if (lane == 0) { sh[0][wave] = s; sh[1][wave] = s2; }
    __syncthreads();
    s  = sh[0][0] + sh[0][1] + sh[0][2] + sh[0][3];
    s2 = sh[1][0] + sh[1][1] + sh[1][2] + sh[1][3];
    float mu  = s * (1.0f / DIM);
    float var = s2 * (1.0f / DIM) - mu * mu;
    float inv = rsqrtf(var + 1e-5f);
    int c0 = threadIdx.x, c1 = threadIdx.x + 256;
    float o0 = (v0 - mu) * inv * g[c0] + bta[c0];
    float o1 = (v1 - mu) * inv * g[c1] + bta[c1];
    outf[(size_t)row * DIM + c0] = o0;
    outf[(size_t)row * DIM + c1] = o1;
    if constexpr (WB) {
        outb[(size_t)row * DIM + c0] = __float2bfloat16(o0);
        outb[(size_t)row * DIM + c1] = __float2bfloat16(o1);
    }
}

extern "C" void kernel_launch(void* const* d_in, const int* in_sizes, int n_in,
                              void* d_out, int out_size, void* d_ws, size_t ws_size,
                              hipStream_t stream)
{
    const float* tensor = (const float*)d_in[0];
    const float* mask   = (const float*)d_in[1];
    const float* tang   = (const float*)d_in[2];
    const float* htd    = (const float*)d_in[3];
    const float* Qw     = (const float*)d_in[4];
    const float* qb     = (const float*)d_in[5];
    // d_in[6], d_in[7] (Kw, Kb) dead code
    const float* Vw     = (const float*)d_in[8];
    const float* Vb     = (const float*)d_in[9];
    const float* Ow     = (const float*)d_in[10];
    const float* Ob     = (const float*)d_in[11];
    const float* g1     = (const float*)d_in[12];
    const float* b1     = (const float*)d_in[13];
    const float* Win    = (const float*)d_in[14];
    const float* bin    = (const float*)d_in[15];
    const float* Wout   = (const float*)d_in[16];
    const float* bout   = (const float*)d_in[17];
    const float* g2     = (const float*)d_in[18];
    const float* b2     = (const float*)d_in[19];
    float* out = (float*)d_out;

    float* ws = (float*)d_ws;
    // f32-unit offsets, layout identical to rounds 8/9 (lifetimes unchanged):
    float* vbuf   = ws + 0;
    bf16*  actb   = (bf16*)(ws + 0);
    bf16*  tensorb= (bf16*)(ws + 2097152);
    bf16*  combb  = tensorb;
    bf16*  timefb = (bf16*)(ws + 3145728);
    bf16*  interb = (bf16*)(ws + 4194304);
    float* wpart  = ws + 5242880;
    float* buf5   = ws + 5242880;
    float* inter  = ws + 7340032;
    bf16*  WTb    = (bf16*)(ws + 9437184);
    float* qs     = ws + 9502720;
    bf16*  QVwT   = (bf16*)(ws + 9535488);
    bf16*  QwT    = QVwT;                         // rows 0..511
    bf16*  VwT    = QVwT + (size_t)512 * 512;     // rows 512..1023
    bf16*  OwT    = (bf16*)(ws + 9797632);
    bf16*  WinT   = (bf16*)(ws + 9928704);
    bf16*  WoutT  = (bf16*)(ws + 10321920);

    // 1. setup: tensor->bf16 + time features + weight transposes
    setup_kernel<<<8448, 256, 0, stream>>>(tensor, tang, htd, Qw, Vw, Ow, Win, Wout,
                                           tensorb, timefb, QwT, VwT, OwT, WinT, WoutT);
    // 2. fused Q+V GEMM (64x128, 512 blocks): qs row-sums + vbuf
    gemm_qv<<<dim3(8, 64), 256, 0, stream>>>(tensorb, QVwT, qb, Vb, qs, vbuf);
    // 3. WT partials (split-K 32)
    wpart_kernel<<<dim3(16, KCH), 256, 0, stream>>>(vbuf, timefb, wpart);
    // 4. reduce -> WT bf16
    wred_kernel<<<512, 256, 0, stream>>>(wpart, WTb);
    // 5. comb via MFMA (256 blocks)
    comb_mfma<<<dim3(16, 16), 256, 0, stream>>>(timefb, WTb, qs, mask, combb);
    // 6. attn_out + residual(tensor) -> preLN1  (64x64, 512 blocks)
    gemm_big<64, 64, 2, float><<<dim3(8, 64), 256, 0, stream>>>(combb, OwT, Ob, tensor, vbuf, ROWS, DIM, DIM);
    // 7. LN1 -> inter f32 + interb bf16
    ln_kernel<1><<<ROWS, 256, 0, stream>>>(vbuf, g1, b1, inter, interb);
    // 8. FFN in + gelu -> bf16  (64x128, 768 blocks)
    gemm_big<64, 128, 3, bf16><<<dim3(12, 64), 256, 0, stream>>>(interb, WinT, bin, nullptr, actb, ROWS, LIND, DIM);
    // 9. FFN out + residual(inter)  (64x64, 512 blocks)
    gemm_big<64, 64, 4, float><<<dim3(8, 64), 256, 0, stream>>>(actb, WoutT, bout, inter, buf5, ROWS, DIM, LIND);
    // 10. LN2 -> f32 output
    ln_kernel<0><<<ROWS, 256, 0, stream>>>(buf5, g2, b2, out, nullptr);
}

// Round 11
// 101.188 us; speedup vs baseline: 1.3923x; 1.2171x over previous
//
#include <hip/hip_runtime.h>
#include <hip/hip_bf16.h>

typedef __hip_bfloat16 bf16;
typedef __attribute__((ext_vector_type(8))) __bf16 bf16x8;
typedef __attribute__((ext_vector_type(4))) float f32x4;

#define DIM   512
#define NH    8
#define HDIM  64
#define LIND  1536
#define LSEQ  2048
#define ROWS  4096        // B*L
#define TF    128         // time features
#define KCH   32          // wpart split-K chunks (BK=64 each)

__device__ __forceinline__ float b2f(bf16 v){ return __bfloat162float(v); }
__device__ __forceinline__ void stc(float* C, size_t i, float v){ C[i] = v; }
__device__ __forceinline__ void stc(bf16*  C, size_t i, float v){ C[i] = __float2bfloat16(v); }

typedef const __attribute__((address_space(1))) unsigned int* gp1_t;
typedef __attribute__((address_space(3))) unsigned int* lp3_t;
__device__ __forceinline__ void gload16(const bf16* g, unsigned short* l) {
    __builtin_amdgcn_global_load_lds((gp1_t)(const void*)g, (lp3_t)(void*)l, 16, 0, 0);
}

// ---------- setup: tensor->bf16 | timef [l][h][d] | timefT [h][d][l] | transposes ----
__global__ __launch_bounds__(256) void setup_kernel(const float* __restrict__ tensor,
                                                    const float* __restrict__ tang,
                                                    const float* __restrict__ htd,
                                                    const float* __restrict__ Qw,
                                                    const float* __restrict__ Vw,
                                                    const float* __restrict__ Ow,
                                                    const float* __restrict__ Win,
                                                    const float* __restrict__ Wout,
                                                    bf16* __restrict__ tensorb,
                                                    bf16* __restrict__ timef,
                                                    bf16* __restrict__ timefT,
                                                    bf16* __restrict__ QwT,
                                                    bf16* __restrict__ VwT,
                                                    bf16* __restrict__ OwT,
                                                    bf16* __restrict__ WinT,
                                                    bf16* __restrict__ WoutT)
{
    int id = blockIdx.x;
    if (id < 2048) {
        int i = id * 256 + threadIdx.x;
        float4 v = ((const float4*)tensor)[i];
        bf16 t[4];
        t[0] = __float2bfloat16(v.x); t[1] = __float2bfloat16(v.y);
        t[2] = __float2bfloat16(v.z); t[3] = __float2bfloat16(v.w);
        *(uint2*)&tensorb[(size_t)i * 4] = *(uint2*)t;
        return;
    }
    if (id < 6144) {
        // timef[l][h][0:128], lanes vary d
        int idx = (id - 2048) * 256 + threadIdx.x;   // < 1048576
        int d = idx & 63;
        int h = (idx >> 6) & 7;
        int l = idx >> 9;
        float ang = ((float)l + htd[h]) * tang[h * 64 + d];
        float s, c;
        sincosf(ang, &s, &c);
        bf16* p = timef + ((size_t)l * NH + h) * TF;
        p[d]      = __float2bfloat16((c + s) * 0.125f);
        p[d + 64] = __float2bfloat16((c - s) * 0.125f);
        return;
    }
    if (id < 10240) {
        // timefT[h][d][l], lanes vary l (coalesced)
        int q = id - 6144;               // 0..4095
        int h  = q >> 9;                 // 8
        int rem = q & 511;
        int d  = rem >> 3;               // 64
        int l  = (rem & 7) * 256 + threadIdx.x;
        float ang = ((float)l + htd[h]) * tang[h * 64 + d];
        float s, c;
        sincosf(ang, &s, &c);
        timefT[((size_t)(h * 128 + d)) * LSEQ + l]      = __float2bfloat16((c + s) * 0.125f);
        timefT[((size_t)(h * 128 + d + 64)) * LSEQ + l] = __float2bfloat16((c - s) * 0.125f);
        return;
    }
    id -= 10240;
    const float* in; bf16* out; int R, C, tx, ty;
    if (id < 256)        { in = Qw;   out = QwT;   R = 512;  C = 512;  tx = id & 15; ty = id >> 4; }
    else if (id < 512)   { id -= 256;  in = Vw;   out = VwT;   R = 512;  C = 512;  tx = id & 15; ty = id >> 4; }
    else if (id < 768)   { id -= 512;  in = Ow;   out = OwT;   R = 512;  C = 512;  tx = id & 15; ty = id >> 4; }
    else if (id < 1536)  { id -= 768;  in = Win;  out = WinT;  R = 512;  C = 1536; tx = id % 48; ty = id / 48; }
    else                 { id -= 1536; in = Wout; out = WoutT; R = 1536; C = 512;  tx = id & 15; ty = id >> 4; }

    __shared__ float t[32][33];
    int bx = tx * 32, by = ty * 32;
    int x = threadIdx.x & 31, y = threadIdx.x >> 5;
    #pragma unroll
    for (int r = 0; r < 32; r += 8)
        t[y + r][x] = in[(size_t)(by + y + r) * C + bx + x];
    __syncthreads();
    #pragma unroll
    for (int r = 0; r < 32; r += 8)
        out[(size_t)(bx + y + r) * R + by + x] = __float2bfloat16(t[x][y + r]);
}

// ===== BK=64 double-buffered MFMA GEMM (both-sides XOR swizzle) =====
// LDS tile [rows][64 k]; staging slot e: row=e>>3, granule g=e&7 holds global
// granule g^(row&7); reads XOR identically -> conflict-free (2-way alias only).

// ---------------- generic GEMM: C = epi(A[M,K] @ Bt[N,K]^T) ----------------
// EPI: 2 = x+b+res (O)   3 = gelu(x+b) (FFN1)   4 = x+b+res (FFN2)
template<int BM, int BN, int EPI, typename OUTT>
__global__ __launch_bounds__(256) void gemm_big(const bf16* __restrict__ A,
                                                const bf16* __restrict__ Bt,
                                                const float* __restrict__ bias,
                                                const float* __restrict__ res,
                                                OUTT* __restrict__ C,
                                                int M, int N, int K)
{
    constexpr int RM = BM / 32, RN = BN / 32;
    constexpr int ITA = BM / 32, ITB = BN / 32;
    __shared__ unsigned short As[2][BM * 64];
    __shared__ unsigned short Bs[2][BN * 64];

    int tid  = threadIdx.x;
    int lane = tid & 63, wave = tid >> 6;
    int wr = wave >> 1, wc = wave & 1;
    int bm = blockIdx.y * BM, bn = blockIdx.x * BN;
    int l15 = lane & 15, lk = lane >> 4;

    const bf16* gA[ITA]; const bf16* gB[ITB];
    #pragma unroll
    for (int it = 0; it < ITA; ++it) {
        int e = it * 256 + tid, row = e >> 3, g = e & 7;
        gA[it] = &A[(size_t)(bm + row) * K + (g ^ (row & 7)) * 8];
    }
    #pragma unroll
    for (int it = 0; it < ITB; ++it) {
        int e = it * 256 + tid, row = e >> 3, g = e & 7;
        gB[it] = &Bt[(size_t)(bn + row) * K + (g ^ (row & 7)) * 8];
    }

    f32x4 acc[RM][RN] = {};
    int NT = K >> 6;

    #pragma unroll
    for (int it = 0; it < ITA; ++it) gload16(gA[it], &As[0][(it * 256 + tid) * 8]);
    #pragma unroll
    for (int it = 0; it < ITB; ++it) gload16(gB[it], &Bs[0][(it * 256 + tid) * 8]);
    __syncthreads();

    for (int t = 0; t < NT; ++t) {
        int cur = t & 1;
        if (t + 1 < NT) {
            #pragma unroll
            for (int it = 0; it < ITA; ++it)
                gload16(gA[it] + (t + 1) * 64, &As[cur ^ 1][(it * 256 + tid) * 8]);
            #pragma unroll
            for (int it = 0; it < ITB; ++it)
                gload16(gB[it] + (t + 1) * 64, &Bs[cur ^ 1][(it * 256 + tid) * 8]);
        }
        #pragma unroll
        for (int s = 0; s < 2; ++s) {
            bf16x8 a[RM], b[RN];
            int g8 = ((s * 4 + lk) ^ (l15 & 7)) * 8;
            #pragma unroll
            for (int m = 0; m < RM; ++m) {
                int row = wr * (BM / 2) + m * 16 + l15;
                a[m] = *(const bf16x8*)&As[cur][row * 64 + g8];
            }
            #pragma unroll
            for (int n = 0; n < RN; ++n) {
                int row = wc * (BN / 2) + n * 16 + l15;
                b[n] = *(const bf16x8*)&Bs[cur][row * 64 + g8];
            }
            #pragma unroll
            for (int m = 0; m < RM; ++m)
                #pragma unroll
                for (int n = 0; n < RN; ++n)
                    acc[m][n] = __builtin_amdgcn_mfma_f32_16x16x32_bf16(a[m], b[n], acc[m][n], 0, 0, 0);
        }
        __syncthreads();
    }

    #pragma unroll
    for (int m = 0; m < RM; ++m) {
        #pragma unroll
        for (int n = 0; n < RN; ++n) {
            int gcol = bn + wc * (BN / 2) + n * 16 + l15;
            float bs = bias[gcol];
            #pragma unroll
            for (int r = 0; r < 4; ++r) {
                int grow = bm + wr * (BM / 2) + m * 16 + lk * 4 + r;
                float x = acc[m][n][r];
                float o;
                if constexpr (EPI == 2) {
                    o = x + bs + res[(size_t)grow * N + gcol];
                } else if constexpr (EPI == 3) {
                    float t = x + bs;
                    float u = t + 0.044715f * t * t * t;
                    o = 0.5f * t * (1.0f + tanhf(0.7978845608028654f * u));
                } else {
                    o = x + bs + res[(size_t)grow * N + gcol];
                }
                stc(C, (size_t)grow * N + gcol, o);
            }
        }
    }
}

// ----- fused Q+V GEMM, BM=64 BN=128: Bt = [QwT;VwT] (1024x512) -----
// Q tiles (bn<512): sigmoid-gate row-sums -> qs.
// V tiles: x + Vb -> vT[col][t] bf16 (transposed, feeds wpart_mfma B-operand).
__global__ __launch_bounds__(256) void gemm_qv(const bf16* __restrict__ A,
                                               const bf16* __restrict__ Bt,
                                               const float* __restrict__ qb,
                                               const float* __restrict__ Vb,
                                               float* __restrict__ qs,
                                               bf16* __restrict__ vT)
{
    constexpr int BM = 64, BN = 128, RM = 2, RN = 4;
    __shared__ unsigned short As[2][BM * 64];
    __shared__ unsigned short Bs[2][BN * 64];
    __shared__ float qsums[2][64];

    const int K = DIM;
    int tid  = threadIdx.x;
    int lane = tid & 63, wave = tid >> 6;
    int wr = wave >> 1, wc = wave & 1;
    int bm = blockIdx.y * BM, bn = blockIdx.x * BN;
    int l15 = lane & 15, lk = lane >> 4;

    const bf16* gA[2]; const bf16* gB[4];
    #pragma unroll
    for (int it = 0; it < 2; ++it) {
        int e = it * 256 + tid, row = e >> 3, g = e & 7;
        gA[it] = &A[(size_t)(bm + row) * K + (g ^ (row & 7)) * 8];
    }
    #pragma unroll
    for (int it = 0; it < 4; ++it) {
        int e = it * 256 + tid, row = e >> 3, g = e & 7;
        gB[it] = &Bt[(size_t)(bn + row) * K + (g ^ (row & 7)) * 8];
    }

    f32x4 acc[RM][RN] = {};
    const int NT = K >> 6;   // 8

    #pragma unroll
    for (int it = 0; it < 2; ++it) gload16(gA[it], &As[0][(it * 256 + tid) * 8]);
    #pragma unroll
    for (int it = 0; it < 4; ++it) gload16(gB[it], &Bs[0][(it * 256 + tid) * 8]);
    __syncthreads();

    for (int t = 0; t < NT; ++t) {
        int cur = t & 1;
        if (t + 1 < NT) {
            #pragma unroll
            for (int it = 0; it < 2; ++it)
                gload16(gA[it] + (t + 1) * 64, &As[cur ^ 1][(it * 256 + tid) * 8]);
            #pragma unroll
            for (int it = 0; it < 4; ++it)
                gload16(gB[it] + (t + 1) * 64, &Bs[cur ^ 1][(it * 256 + tid) * 8]);
        }
        #pragma unroll
        for (int s = 0; s < 2; ++s) {
            bf16x8 a[RM], b[RN];
            int g8 = ((s * 4 + lk) ^ (l15 & 7)) * 8;
            #pragma unroll
            for (int m = 0; m < RM; ++m) {
                int row = wr * 32 + m * 16 + l15;
                a[m] = *(const bf16x8*)&As[cur][row * 64 + g8];
            }
            #pragma unroll
            for (int n = 0; n < RN; ++n) {
                int row = wc * 64 + n * 16 + l15;
                b[n] = *(const bf16x8*)&Bs[cur][row * 64 + g8];
            }
            #pragma unroll
            for (int m = 0; m < RM; ++m)
                #pragma unroll
                for (int n = 0; n < RN; ++n)
                    acc[m][n] = __builtin_amdgcn_mfma_f32_16x16x32_bf16(a[m], b[n], acc[m][n], 0, 0, 0);
        }
        __syncthreads();
    }

    if (bn < DIM) {
        // Q gate: sigmoid(x - exp(qb))/64, summed over this wave's head (64 cols)
        float eq[RN];
        #pragma unroll
        for (int n = 0; n < RN; ++n)
            eq[n] = expf(qb[bn + wc * 64 + n * 16 + l15]);
        #pragma unroll
        for (int m = 0; m < RM; ++m) {
            #pragma unroll
            for (int r = 0; r < 4; ++r) {
                float s = 0.f;
                #pragma unroll
                for (int n = 0; n < RN; ++n) {
                    float x = acc[m][n][r] - eq[n];
                    s += 1.0f / (1.0f + expf(-x));
                }
                s *= (1.0f / 64.0f);
                #pragma unroll
                for (int off = 1; off < 16; off <<= 1) s += __shfl_xor(s, off);
                if (l15 == 0)
                    qsums[wc][wr * 32 + m * 16 + lk * 4 + r] = s;
            }
        }
        __syncthreads();
        if (tid < 128) {
            int hh = tid >> 6, row = tid & 63;
            qs[(size_t)(bm + row) * NH + (bn >> 6) + hh] = qsums[hh][row];
        }
    } else {
        // V -> vT[col][t], bf16, 4 contiguous t per store
        #pragma unroll
        for (int m = 0; m < RM; ++m) {
            int grow0 = bm + wr * 32 + m * 16 + lk * 4;
            #pragma unroll
            for (int n = 0; n < RN; ++n) {
                int gcol = bn - DIM + wc * 64 + n * 16 + l15;
                float bs = Vb[gcol];
                bf16 tmp[4];
                #pragma unroll
                for (int r = 0; r < 4; ++r)
                    tmp[r] = __float2bfloat16(acc[m][n][r] + bs);
                *(uint2*)&vT[(size_t)gcol * ROWS + grow0] = *(uint2*)tmp;
            }
        }
    }
}

// ---- wpart_mfma: per (bh, kc) one BK=64 t-slab of WT_partial[d][hd] -------
// A = timefT[h] [128 d][2048 t], Bt = vT [h*64+hd][4096 t] (slice b*2048+kc*64)
// C[d][hd] stored transposed as partial [hd][d] (f32x4 over d).
__global__ __launch_bounds__(256) void wpart_mfma(const bf16* __restrict__ timefT,
                                                  const bf16* __restrict__ vT,
                                                  float* __restrict__ wpart)
{
    __shared__ unsigned short As[128 * 64];
    __shared__ unsigned short Bs[64 * 64];

    int bh = blockIdx.x;              // 0..15
    int kc = blockIdx.y;              // 0..31
    int b = bh >> 3, h = bh & 7;
    int tid  = threadIdx.x;
    int lane = tid & 63, wave = tid >> 6;
    int wr = wave >> 1, wc = wave & 1;
    int l15 = lane & 15, lk = lane >> 4;
    int k0 = kc * 64;

    const bf16* Abase = timefT + (size_t)h * (128 * LSEQ) + k0;
    const bf16* Bbase = vT + (size_t)h * 64 * ROWS + (size_t)b * LSEQ + k0;

    #pragma unroll
    for (int it = 0; it < 4; ++it) {
        int e = it * 256 + tid, row = e >> 3, g = e & 7;
        gload16(Abase + (size_t)row * LSEQ + (g ^ (row & 7)) * 8, &As[e * 8]);
    }
    #pragma unroll
    for (int it = 0; it < 2; ++it) {
        int e = it * 256 + tid, row = e >> 3, g = e & 7;
        gload16(Bbase + (size_t)row * ROWS + (g ^ (row & 7)) * 8, &Bs[e * 8]);
    }
    __syncthreads();

    f32x4 acc[4][2] = {};
    #pragma unroll
    for (int s = 0; s < 2; ++s) {
        bf16x8 a[4], bv[2];
        int g8 = ((s * 4 + lk) ^ (l15 & 7)) * 8;
        #pragma unroll
        for (int m = 0; m < 4; ++m) {
            int row = wr * 64 + m * 16 + l15;
            a[m] = *(const bf16x8*)&As[row * 64 + g8];
        }
        #pragma unroll
        for (int n = 0; n < 2; ++n) {
            int row = wc * 32 + n * 16 + l15;
            bv[n] = *(const bf16x8*)&Bs[row * 64 + g8];
        }
        #pragma unroll
        for (int m = 0; m < 4; ++m)
            #pragma unroll
            for (int n = 0; n < 2; ++n)
                acc[m][n] = __builtin_amdgcn_mfma_f32_16x16x32_bf16(a[m], bv[n], acc[m][n], 0, 0, 0);
    }

    float* wp = wpart + ((size_t)(kc * 16 + bh)) * (HDIM * TF);
    #pragma unroll
    for (int m = 0; m < 4; ++m) {
        int gd0 = wr * 64 + m * 16 + lk * 4;
        #pragma unroll
        for (int n = 0; n < 2; ++n) {
            int ghd = wc * 32 + n * 16 + l15;
            *(f32x4*)&wp[ghd * TF + gd0] = acc[m][n];
        }
    }
}

__global__ __launch_bounds__(256) void wred_kernel(const float* __restrict__ wpart,
                                                   bf16* __restrict__ WT)
{
    int i = blockIdx.x * 256 + threadIdx.x;   // < 131072 over [bh][hd][d]
    float s = 0.f;
    #pragma unroll
    for (int kc = 0; kc < KCH; ++kc)
        s += wpart[(size_t)kc * 131072 + i];
    WT[i] = __float2bfloat16(s);
}

// ---- comb[b,l,h,:] = qs[l,h]*mask[l] * (time[l,h,:] @ WT[bh]^T), MFMA ------
__global__ __launch_bounds__(256) void comb_mfma(const bf16* __restrict__ timef,
                                                 const bf16* __restrict__ WT,
                                                 const float* __restrict__ qs,
                                                 const float* __restrict__ mask,
                                                 bf16* __restrict__ comb)
{
    int bh = blockIdx.x;
    int b = bh >> 3, h = bh & 7;
    int lane = threadIdx.x & 63, wave = threadIdx.x >> 6;
    int l15 = lane & 15, lk = lane >> 4;
    int lbase = blockIdx.y * 128 + wave * 32;

    const bf16* wt = WT + (size_t)bh * (HDIM * TF);

    f32x4 acc[2][4] = {};
    #pragma unroll
    for (int ks = 0; ks < 4; ++ks) {
        int kt = ks * 32;
        bf16x8 a[2], bf[4];
        #pragma unroll
        for (int m = 0; m < 2; ++m) {
            int l = lbase + m * 16 + l15;
            a[m] = *(const bf16x8*)&timef[((size_t)l * NH + h) * TF + kt + lk * 8];
        }
        #pragma unroll
        for (int n = 0; n < 4; ++n)
            bf[n] = *(const bf16x8*)&wt[(size_t)(n * 16 + l15) * TF + kt + lk * 8];
        #pragma unroll
        for (int m = 0; m < 2; ++m)
            #pragma unroll
            for (int n = 0; n < 4; ++n)
                acc[m][n] = __builtin_amdgcn_mfma_f32_16x16x32_bf16(a[m], bf[n], acc[m][n], 0, 0, 0);
    }

    #pragma unroll
    for (int m = 0; m < 2; ++m) {
        #pragma unroll
        for (int r = 0; r < 4; ++r) {
            int l = lbase + m * 16 + lk * 4 + r;
            int row = b * LSEQ + l;
            float q = qs[(size_t)row * NH + h] * mask[row];
            #pragma unroll
            for (int n = 0; n < 4; ++n) {
                int hd = n * 16 + l15;
                comb[(size_t)row * DIM + h * HDIM + hd] =
                    __float2bfloat16(q * acc[m][n][r]);
            }
        }
    }
}

// ---------------- LayerNorm over last dim (512) ----------------
template<int WB>
__global__ __launch_bounds__(256) void ln_kernel(const float* __restrict__ X,
                                                 const float* __restrict__ g,
                                                 const float* __restrict__ bta,
                                                 float* __restrict__ outf,
                                                 bf16* __restrict__ outb)
{
    int row = blockIdx.x;
    const float* x = X + (size_t)row * DIM;
    float v0 = x[threadIdx.x], v1 = x[threadIdx.x + 256];
    float s = v0 + v1, s2 = v0 * v0 + v1 * v1;
    #pragma unroll
    for (int off = 1; off < 64; off <<= 1) {
        s  += __shfl_xor(s,  off);
        s2 += __shfl_xor(s2, off);
    }
    __shared__ float sh[2][4];
    int wave = threadIdx.x >> 6, lane = threadIdx.x & 63;
    if (lane == 0) { sh[0][wave] = s; sh[1][wave] = s2; }
    __syncthreads();
    s  = sh[0][0] + sh[0][1] + sh[0][2] + sh[0][3];
    s2 = sh[1][0] + sh[1][1] + sh[1][2] + sh[1][3];
    float mu  = s * (1.0f / DIM);
    float var = s2 * (1.0f / DIM) - mu * mu;
    float inv = rsqrtf(var + 1e-5f);
    int c0 = threadIdx.x, c1 = threadIdx.x + 256;
    float o0 = (v0 - mu) * inv * g[c0] + bta[c0];
    float o1 = (v1 - mu) * inv * g[c1] + bta[c1];
    outf[(size_t)row * DIM + c0] = o0;
    outf[(size_t)row * DIM + c1] = o1;
    if constexpr (WB) {
        outb[(size_t)row * DIM + c0] = __float2bfloat16(o0);
        outb[(size_t)row * DIM + c1] = __float2bfloat16(o1);
    }
}

extern "C" void kernel_launch(void* const* d_in, const int* in_sizes, int n_in,
                              void* d_out, int out_size, void* d_ws, size_t ws_size,
                              hipStream_t stream)
{
    const float* tensor = (const float*)d_in[0];
    const float* mask   = (const float*)d_in[1];
    const float* tang   = (const float*)d_in[2];
    const float* htd    = (const float*)d_in[3];
    const float* Qw     = (const float*)d_in[4];
    const float* qb     = (const float*)d_in[5];
    // d_in[6], d_in[7] (Kw, Kb) dead code
    const float* Vw     = (const float*)d_in[8];
    const float* Vb     = (const float*)d_in[9];
    const float* Ow     = (const float*)d_in[10];
    const float* Ob     = (const float*)d_in[11];
    const float* g1     = (const float*)d_in[12];
    const float* b1     = (const float*)d_in[13];
    const float* Win    = (const float*)d_in[14];
    const float* bin    = (const float*)d_in[15];
    const float* Wout   = (const float*)d_in[16];
    const float* bout   = (const float*)d_in[17];
    const float* g2     = (const float*)d_in[18];
    const float* b2     = (const float*)d_in[19];
    float* out = (float*)d_out;

    float* ws = (float*)d_ws;
    // f32-unit offsets. Steps: s1 setup, s2 qv, s3 wpart, s4 wred, s5 comb,
    // s6 O, s7 LN1, s8 ffn1, s9 ffn2, s10 LN2. Lifetimes (write -> last read):
    //   vT      [0,        1048576)  bf16 [512][4096]: s2->s3
    //   actb    [0,        3145728)  bf16 FFN act: s8->s9   (vT/tensorb/timefb dead)
    //   tensorb [1048576,  2097152)  s1->s2; combb reuse: s5->s6
    //   timefb  [2097152,  3145728)  s1->s5
    //   timefT  [3145728,  4194304)  bf16 [8][128][2048]: s1->s3
    //   interb  [3145728,  4194304)  bf16 reuse: s7->s8
    //   wpart   [4194304,  8388608)  f32 32x131072: s3->s4
    //   preLN1  [4194304,  6291456)  reuse: s6->s7
    //   buf5    [6291456,  8388608)  preLN2 reuse: s9->s10
    //   inter   [8388608, 10485760)  f32: s7->s9
    //   WTb     [10485760, 10551296) bf16: s4->s5
    //   qs      [10551296, 10584064) f32:  s2->s5
    //   QVwT    [10584064, 10846208) bf16 [1024][512]: s1->s2
    //   OwT     [10846208, 10977280) s1->s6
    //   WinT    [10977280, 11370496) s1->s8
    //   WoutT   [11370496, 11763712) s1->s9
    // peak = 11763712 f32 = 47.05 MB (<= 47.2 MB proven round 5)
    bf16*  vT     = (bf16*)(ws + 0);
    bf16*  actb   = (bf16*)(ws + 0);
    bf16*  tensorb= (bf16*)(ws + 1048576);
    bf16*  combb  = tensorb;
    bf16*  timefb = (bf16*)(ws + 2097152);
    bf16*  timefT = (bf16*)(ws + 3145728);
    bf16*  interb = (bf16*)(ws + 3145728);
    float* wpart  = ws + 4194304;
    float* preLN1 = ws + 4194304;
    float* buf5   = ws + 6291456;
    float* inter  = ws + 8388608;
    bf16*  WTb    = (bf16*)(ws + 10485760);
    float* qs     = ws + 10551296;
    bf16*  QVwT   = (bf16*)(ws + 10584064);
    bf16*  QwT    = QVwT;                         // rows 0..511
    bf16*  VwT    = QVwT + (size_t)512 * 512;     // rows 512..1023
    bf16*  OwT    = (bf16*)(ws + 10846208);
    bf16*  WinT   = (bf16*)(ws + 10977280);
    bf16*  WoutT  = (bf16*)(ws + 11370496);

    // 1. setup: tensor->bf16 + timef + timefT + weight transposes
    setup_kernel<<<12544, 256, 0, stream>>>(tensor, tang, htd, Qw, Vw, Ow, Win, Wout,
                                            tensorb, timefb, timefT, QwT, VwT, OwT, WinT, WoutT);
    // 2. fused Q+V GEMM (64x128, 512 blocks): qs row-sums + vT bf16
    gemm_qv<<<dim3(8, 64), 256, 0, stream>>>(tensorb, QVwT, qb, Vb, qs, vT);
    // 3. WT partials via MFMA (split-K 32, 512 blocks)
    wpart_mfma<<<dim3(16, KCH), 256, 0, stream>>>(timefT, vT, wpart);
    // 4. reduce -> WT bf16
    wred_kernel<<<512, 256, 0, stream>>>(wpart, WTb);
    // 5. comb via MFMA (256 blocks)
    comb_mfma<<<dim3(16, 16), 256, 0, stream>>>(timefb, WTb, qs, mask, combb);
    // 6. attn_out + residual(tensor) -> preLN1  (64x64, 512 blocks)
    gemm_big<64, 64, 2, float><<<dim3(8, 64), 256, 0, stream>>>(combb, OwT, Ob, tensor, preLN1, ROWS, DIM, DIM);
    // 7. LN1 -> inter f32 + interb bf16
    ln_kernel<1><<<ROWS, 256, 0, stream>>>(preLN1, g1, b1, inter, interb);
    // 8. FFN in + gelu -> bf16  (64x128, 768 blocks)
    gemm_big<64, 128, 3, bf16><<<dim3(12, 64), 256, 0, stream>>>(interb, WinT, bin, nullptr, actb, ROWS, LIND, DIM);
    // 9. FFN out + residual(inter)  (64x64, 512 blocks)
    gemm_big<64, 64, 4, float><<<dim3(8, 64), 256, 0, stream>>>(actb, WoutT, bout, inter, buf5, ROWS, DIM, LIND);
    // 10. LN2 -> f32 output
    ln_kernel<0><<<ROWS, 256, 0, stream>>>(buf5, g2, b2, out, nullptr);
}

// Round 12
// 98.783 us; speedup vs baseline: 1.4262x; 1.0243x over previous
//
#include <hip/hip_runtime.h>
#include <hip/hip_bf16.h>

typedef __hip_bfloat16 bf16;
typedef __attribute__((ext_vector_type(8))) __bf16 bf16x8;
typedef __attribute__((ext_vector_type(4))) float f32x4;

#define DIM   512
#define NH    8
#define HDIM  64
#define LIND  1536
#define LSEQ  2048
#define ROWS  4096        // B*L
#define TF    128         // time features
#define KCH   32          // wpart split-K chunks (BK=64 each)

__device__ __forceinline__ float b2f(bf16 v){ return __bfloat162float(v); }
__device__ __forceinline__ void stc(float* C, size_t i, float v){ C[i] = v; }
__device__ __forceinline__ void stc(bf16*  C, size_t i, float v){ C[i] = __float2bfloat16(v); }
__device__ __forceinline__ float ldr(const float* p, size_t i){ return p[i]; }
__device__ __forceinline__ float ldr(const bf16*  p, size_t i){ return b2f(p[i]); }

typedef const __attribute__((address_space(1))) unsigned int* gp1_t;
typedef __attribute__((address_space(3))) unsigned int* lp3_t;
__device__ __forceinline__ void gload16(const bf16* g, unsigned short* l) {
    __builtin_amdgcn_global_load_lds((gp1_t)(const void*)g, (lp3_t)(void*)l, 16, 0, 0);
}

// ---------- setup: tensor->bf16 | time (both layouts, 1 sincos) | transposes ----
__global__ __launch_bounds__(256) void setup_kernel(const float* __restrict__ tensor,
                                                    const float* __restrict__ tang,
                                                    const float* __restrict__ htd,
                                                    const float* __restrict__ Qw,
                                                    const float* __restrict__ Vw,
                                                    const float* __restrict__ Ow,
                                                    const float* __restrict__ Win,
                                                    const float* __restrict__ Wout,
                                                    bf16* __restrict__ tensorb,
                                                    bf16* __restrict__ timef,
                                                    bf16* __restrict__ timefT,
                                                    bf16* __restrict__ QwT,
                                                    bf16* __restrict__ VwT,
                                                    bf16* __restrict__ OwT,
                                                    bf16* __restrict__ WinT,
                                                    bf16* __restrict__ WoutT)
{
    __shared__ unsigned short st0[32][33];
    __shared__ unsigned short st1[32][33];
    __shared__ float t[32][33];

    int id = blockIdx.x;
    if (id < 2048) {
        int i = id * 256 + threadIdx.x;
        float4 v = ((const float4*)tensor)[i];
        bf16 tt[4];
        tt[0] = __float2bfloat16(v.x); tt[1] = __float2bfloat16(v.y);
        tt[2] = __float2bfloat16(v.z); tt[3] = __float2bfloat16(v.w);
        *(uint2*)&tensorb[(size_t)i * 4] = *(uint2*)tt;
        return;
    }
    if (id < 3072) {
        // time features: block (h, dblk in [0,2), lblk in [0,64)); 32d x 32l tile,
        // one sincos per (l,h,d); timef written direct, timefT via LDS transpose.
        int q = id - 2048;              // 0..1023
        int h = q >> 7;                 // 8
        int dblk = (q >> 6) & 1;        // 2
        int lblk = q & 63;              // 64
        int d0 = dblk * 32, l0 = lblk * 32;
        int x = threadIdx.x & 31, y = threadIdx.x >> 5;   // x: d-offset, y: l-base
        float ta = tang[h * 64 + d0 + x];
        float hb = htd[h];
        #pragma unroll
        for (int r = 0; r < 4; ++r) {
            int ll = y + 8 * r;                  // l-local
            float ang = ((float)(l0 + ll) + hb) * ta;
            float s, c;
            sincosf(ang, &s, &c);
            bf16 v0 = __float2bfloat16((c + s) * 0.125f);
            bf16 v1 = __float2bfloat16((c - s) * 0.125f);
            bf16* p = timef + ((size_t)(l0 + ll) * NH + h) * TF;
            p[d0 + x]      = v0;
            p[d0 + x + 64] = v1;
            st0[x][ll] = *(unsigned short*)&v0;
            st1[x][ll] = *(unsigned short*)&v1;
        }
        __syncthreads();
        // transpose out: x = l-local, rows = d-local
        #pragma unroll
        for (int r = 0; r < 4; ++r) {
            int dd = y + 8 * r;
            unsigned short u0 = st0[dd][x], u1 = st1[dd][x];
            timefT[((size_t)(h * 128 + d0 + dd)) * LSEQ + l0 + x]      = *(bf16*)&u0;
            timefT[((size_t)(h * 128 + d0 + dd + 64)) * LSEQ + l0 + x] = *(bf16*)&u1;
        }
        return;
    }
    id -= 3072;
    const float* in; bf16* out; int R, C, tx, ty;
    if (id < 256)        { in = Qw;   out = QwT;   R = 512;  C = 512;  tx = id & 15; ty = id >> 4; }
    else if (id < 512)   { id -= 256;  in = Vw;   out = VwT;   R = 512;  C = 512;  tx = id & 15; ty = id >> 4; }
    else if (id < 768)   { id -= 512;  in = Ow;   out = OwT;   R = 512;  C = 512;  tx = id & 15; ty = id >> 4; }
    else if (id < 1536)  { id -= 768;  in = Win;  out = WinT;  R = 512;  C = 1536; tx = id % 48; ty = id / 48; }
    else                 { id -= 1536; in = Wout; out = WoutT; R = 1536; C = 512;  tx = id & 15; ty = id >> 4; }

    int bx = tx * 32, by = ty * 32;
    int x = threadIdx.x & 31, y = threadIdx.x >> 5;
    #pragma unroll
    for (int r = 0; r < 32; r += 8)
        t[y + r][x] = in[(size_t)(by + y + r) * C + bx + x];
    __syncthreads();
    #pragma unroll
    for (int r = 0; r < 32; r += 8)
        out[(size_t)(bx + y + r) * R + by + x] = __float2bfloat16(t[x][y + r]);
}

// ===== BK=64 double-buffered MFMA GEMM (both-sides XOR swizzle) =====
// EPI: 2 = x+b+res (O)   3 = gelu(x+b) (FFN1)   4 = x+b+res (FFN2, bf16 res)
template<int BM, int BN, int EPI, typename OUTT, typename REST>
__global__ __launch_bounds__(256) void gemm_big(const bf16* __restrict__ A,
                                                const bf16* __restrict__ Bt,
                                                const float* __restrict__ bias,
                                                const REST* __restrict__ res,
                                                OUTT* __restrict__ C,
                                                int M, int N, int K)
{
    constexpr int RM = BM / 32, RN = BN / 32;
    constexpr int ITA = BM / 32, ITB = BN / 32;
    __shared__ unsigned short As[2][BM * 64];
    __shared__ unsigned short Bs[2][BN * 64];

    int tid  = threadIdx.x;
    int lane = tid & 63, wave = tid >> 6;
    int wr = wave >> 1, wc = wave & 1;
    int bm = blockIdx.y * BM, bn = blockIdx.x * BN;
    int l15 = lane & 15, lk = lane >> 4;

    const bf16* gA[ITA]; const bf16* gB[ITB];
    #pragma unroll
    for (int it = 0; it < ITA; ++it) {
        int e = it * 256 + tid, row = e >> 3, g = e & 7;
        gA[it] = &A[(size_t)(bm + row) * K + (g ^ (row & 7)) * 8];
    }
    #pragma unroll
    for (int it = 0; it < ITB; ++it) {
        int e = it * 256 + tid, row = e >> 3, g = e & 7;
        gB[it] = &Bt[(size_t)(bn + row) * K + (g ^ (row & 7)) * 8];
    }

    f32x4 acc[RM][RN] = {};
    int NT = K >> 6;

    #pragma unroll
    for (int it = 0; it < ITA; ++it) gload16(gA[it], &As[0][(it * 256 + tid) * 8]);
    #pragma unroll
    for (int it = 0; it < ITB; ++it) gload16(gB[it], &Bs[0][(it * 256 + tid) * 8]);
    __syncthreads();

    for (int t = 0; t < NT; ++t) {
        int cur = t & 1;
        if (t + 1 < NT) {
            #pragma unroll
            for (int it = 0; it < ITA; ++it)
                gload16(gA[it] + (t + 1) * 64, &As[cur ^ 1][(it * 256 + tid) * 8]);
            #pragma unroll
            for (int it = 0; it < ITB; ++it)
                gload16(gB[it] + (t + 1) * 64, &Bs[cur ^ 1][(it * 256 + tid) * 8]);
        }
        #pragma unroll
        for (int s = 0; s < 2; ++s) {
            bf16x8 a[RM], b[RN];
            int g8 = ((s * 4 + lk) ^ (l15 & 7)) * 8;
            #pragma unroll
            for (int m = 0; m < RM; ++m) {
                int row = wr * (BM / 2) + m * 16 + l15;
                a[m] = *(const bf16x8*)&As[cur][row * 64 + g8];
            }
            #pragma unroll
            for (int n = 0; n < RN; ++n) {
                int row = wc * (BN / 2) + n * 16 + l15;
                b[n] = *(const bf16x8*)&Bs[cur][row * 64 + g8];
            }
            #pragma unroll
            for (int m = 0; m < RM; ++m)
                #pragma unroll
                for (int n = 0; n < RN; ++n)
                    acc[m][n] = __builtin_amdgcn_mfma_f32_16x16x32_bf16(a[m], b[n], acc[m][n], 0, 0, 0);
        }
        __syncthreads();
    }

    #pragma unroll
    for (int m = 0; m < RM; ++m) {
        #pragma unroll
        for (int n = 0; n < RN; ++n) {
            int gcol = bn + wc * (BN / 2) + n * 16 + l15;
            float bs = bias[gcol];
            #pragma unroll
            for (int r = 0; r < 4; ++r) {
                int grow = bm + wr * (BM / 2) + m * 16 + lk * 4 + r;
                float x = acc[m][n][r];
                float o;
                if constexpr (EPI == 2) {
                    o = x + bs + ldr(res, (size_t)grow * N + gcol);
                } else if constexpr (EPI == 3) {
                    float t = x + bs;
                    float u = t + 0.044715f * t * t * t;
                    o = 0.5f * t * (1.0f + tanhf(0.7978845608028654f * u));
                } else {
                    o = x + bs + ldr(res, (size_t)grow * N + gcol);
                }
                stc(C, (size_t)grow * N + gcol, o);
            }
        }
    }
}

// ----- fused Q+V GEMM, BM=64 BN=128: Bt = [QwT;VwT] (1024x512) -----
// Q tiles: sigmoid-gate row-sums -> qs. V tiles: x+Vb -> vT[col][t] bf16,
// coalesced via LDS transpose (reuses Bs).
__global__ __launch_bounds__(256) void gemm_qv(const bf16* __restrict__ A,
                                               const bf16* __restrict__ Bt,
                                               const float* __restrict__ qb,
                                               const float* __restrict__ Vb,
                                               float* __restrict__ qs,
                                               bf16* __restrict__ vT)
{
    constexpr int BM = 64, BN = 128, RM = 2, RN = 4;
    __shared__ unsigned short As[2][BM * 64];
    __shared__ unsigned short Bs[2][BN * 64];
    __shared__ float qsums[2][64];

    const int K = DIM;
    int tid  = threadIdx.x;
    int lane = tid & 63, wave = tid >> 6;
    int wr = wave >> 1, wc = wave & 1;
    int bm = blockIdx.y * BM, bn = blockIdx.x * BN;
    int l15 = lane & 15, lk = lane >> 4;

    const bf16* gA[2]; const bf16* gB[4];
    #pragma unroll
    for (int it = 0; it < 2; ++it) {
        int e = it * 256 + tid, row = e >> 3, g = e & 7;
        gA[it] = &A[(size_t)(bm + row) * K + (g ^ (row & 7)) * 8];
    }
    #pragma unroll
    for (int it = 0; it < 4; ++it) {
        int e = it * 256 + tid, row = e >> 3, g = e & 7;
        gB[it] = &Bt[(size_t)(bn + row) * K + (g ^ (row & 7)) * 8];
    }

    f32x4 acc[RM][RN] = {};
    const int NT = K >> 6;   // 8

    #pragma unroll
    for (int it = 0; it < 2; ++it) gload16(gA[it], &As[0][(it * 256 + tid) * 8]);
    #pragma unroll
    for (int it = 0; it < 4; ++it) gload16(gB[it], &Bs[0][(it * 256 + tid) * 8]);
    __syncthreads();

    for (int t = 0; t < NT; ++t) {
        int cur = t & 1;
        if (t + 1 < NT) {
            #pragma unroll
            for (int it = 0; it < 2; ++it)
                gload16(gA[it] + (t + 1) * 64, &As[cur ^ 1][(it * 256 + tid) * 8]);
            #pragma unroll
            for (int it = 0; it < 4; ++it)
                gload16(gB[it] + (t + 1) * 64, &Bs[cur ^ 1][(it * 256 + tid) * 8]);
        }
        #pragma unroll
        for (int s = 0; s < 2; ++s) {
            bf16x8 a[RM], b[RN];
            int g8 = ((s * 4 + lk) ^ (l15 & 7)) * 8;
            #pragma unroll
            for (int m = 0; m < RM; ++m) {
                int row = wr * 32 + m * 16 + l15;
                a[m] = *(const bf16x8*)&As[cur][row * 64 + g8];
            }
            #pragma unroll
            for (int n = 0; n < RN; ++n) {
                int row = wc * 64 + n * 16 + l15;
                b[n] = *(const bf16x8*)&Bs[cur][row * 64 + g8];
            }
            #pragma unroll
            for (int m = 0; m < RM; ++m)
                #pragma unroll
                for (int n = 0; n < RN; ++n)
                    acc[m][n] = __builtin_amdgcn_mfma_f32_16x16x32_bf16(a[m], b[n], acc[m][n], 0, 0, 0);
        }
        __syncthreads();
    }

    if (bn < DIM) {
        // Q gate: sigmoid(x - exp(qb))/64, summed over this wave's head (64 cols)
        float eq[RN];
        #pragma unroll
        for (int n = 0; n < RN; ++n)
            eq[n] = expf(qb[bn + wc * 64 + n * 16 + l15]);
        #pragma unroll
        for (int m = 0; m < RM; ++m) {
            #pragma unroll
            for (int r = 0; r < 4; ++r) {
                float s = 0.f;
                #pragma unroll
                for (int n = 0; n < RN; ++n) {
                    float x = acc[m][n][r] - eq[n];
                    s += 1.0f / (1.0f + expf(-x));
                }
                s *= (1.0f / 64.0f);
                #pragma unroll
                for (int off = 1; off < 16; off <<= 1) s += __shfl_xor(s, off);
                if (l15 == 0)
                    qsums[wc][wr * 32 + m * 16 + lk * 4 + r] = s;
            }
        }
        __syncthreads();
        if (tid < 128) {
            int hh = tid >> 6, row = tid & 63;
            qs[(size_t)(bm + row) * NH + (bn >> 6) + hh] = qsums[hh][row];
        }
    } else {
        // V -> vT[col][t] via LDS transpose (Bs is dead after last barrier)
        unsigned short* tb = &Bs[0][0];        // layout [128 col][72 t-pad]
        #pragma unroll
        for (int m = 0; m < RM; ++m) {
            int trow0 = wr * 32 + m * 16 + lk * 4;
            #pragma unroll
            for (int n = 0; n < RN; ++n) {
                int col = wc * 64 + n * 16 + l15;
                float bs = Vb[bn - DIM + col];
                bf16 tmp[4];
                #pragma unroll
                for (int r = 0; r < 4; ++r)
                    tmp[r] = __float2bfloat16(acc[m][n][r] + bs);
                *(uint2*)&tb[col * 72 + trow0] = *(uint2*)tmp;
            }
        }
        __syncthreads();
        #pragma unroll
        for (int rep = 0; rep < 8; ++rep) {
            int idx = rep * 256 + tid;        // < 2048
            int col = idx >> 4;               // 0..127
            int t4  = (idx & 15) * 4;         // 0..60
            uint2 v = *(uint2*)&tb[col * 72 + t4];
            *(uint2*)&vT[(size_t)(bn - DIM + col) * ROWS + bm + t4] = v;
        }
    }
}

// ---- wpart_mfma: per (bh, kc) one BK=64 t-slab of WT_partial ----
__global__ __launch_bounds__(256) void wpart_mfma(const bf16* __restrict__ timefT,
                                                  const bf16* __restrict__ vT,
                                                  float* __restrict__ wpart)
{
    __shared__ unsigned short As[128 * 64];
    __shared__ unsigned short Bs[64 * 64];

    int bh = blockIdx.x;              // 0..15
    int kc = blockIdx.y;              // 0..31
    int b = bh >> 3, h = bh & 7;
    int tid  = threadIdx.x;
    int lane = tid & 63, wave = tid >> 6;
    int wr = wave >> 1, wc = wave & 1;
    int l15 = lane & 15, lk = lane >> 4;
    int k0 = kc * 64;

    const bf16* Abase = timefT + (size_t)h * (128 * LSEQ) + k0;
    const bf16* Bbase = vT + (size_t)h * 64 * ROWS + (size_t)b * LSEQ + k0;

    #pragma unroll
    for (int it = 0; it < 4; ++it) {
        int e = it * 256 + tid, row = e >> 3, g = e & 7;
        gload16(Abase + (size_t)row * LSEQ + (g ^ (row & 7)) * 8, &As[e * 8]);
    }
    #pragma unroll
    for (int it = 0; it < 2; ++it) {
        int e = it * 256 + tid, row = e >> 3, g = e & 7;
        gload16(Bbase + (size_t)row * ROWS + (g ^ (row & 7)) * 8, &Bs[e * 8]);
    }
    __syncthreads();

    f32x4 acc[4][2] = {};
    #pragma unroll
    for (int s = 0; s < 2; ++s) {
        bf16x8 a[4], bv[2];
        int g8 = ((s * 4 + lk) ^ (l15 & 7)) * 8;
        #pragma unroll
        for (int m = 0; m < 4; ++m) {
            int row = wr * 64 + m * 16 + l15;
            a[m] = *(const bf16x8*)&As[row * 64 + g8];
        }
        #pragma unroll
        for (int n = 0; n < 2; ++n) {
            int row = wc * 32 + n * 16 + l15;
            bv[n] = *(const bf16x8*)&Bs[row * 64 + g8];
        }
        #pragma unroll
        for (int m = 0; m < 4; ++m)
            #pragma unroll
            for (int n = 0; n < 2; ++n)
                acc[m][n] = __builtin_amdgcn_mfma_f32_16x16x32_bf16(a[m], bv[n], acc[m][n], 0, 0, 0);
    }

    float* wp = wpart + ((size_t)(kc * 16 + bh)) * (HDIM * TF);
    #pragma unroll
    for (int m = 0; m < 4; ++m) {
        int gd0 = wr * 64 + m * 16 + lk * 4;
        #pragma unroll
        for (int n = 0; n < 2; ++n) {
            int ghd = wc * 32 + n * 16 + l15;
            *(f32x4*)&wp[ghd * TF + gd0] = acc[m][n];
        }
    }
}

__global__ __launch_bounds__(256) void wred_kernel(const float* __restrict__ wpart,
                                                   bf16* __restrict__ WT)
{
    int i = blockIdx.x * 256 + threadIdx.x;   // < 131072 over [bh][hd][d]
    float s = 0.f;
    #pragma unroll
    for (int kc = 0; kc < KCH; ++kc)
        s += wpart[(size_t)kc * 131072 + i];
    WT[i] = __float2bfloat16(s);
}

// ---- comb[b,l,h,:] = qs[l,h]*mask[l] * (time[l,h,:] @ WT[bh]^T), MFMA ------
__global__ __launch_bounds__(256) void comb_mfma(const bf16* __restrict__ timef,
                                                 const bf16* __restrict__ WT,
                                                 const float* __restrict__ qs,
                                                 const float* __restrict__ mask,
                                                 bf16* __restrict__ comb)
{
    int bh = blockIdx.x;
    int b = bh >> 3, h = bh & 7;
    int lane = threadIdx.x & 63, wave = threadIdx.x >> 6;
    int l15 = lane & 15, lk = lane >> 4;
    int lbase = blockIdx.y * 128 + wave * 32;

    const bf16* wt = WT + (size_t)bh * (HDIM * TF);

    f32x4 acc[2][4] = {};
    #pragma unroll
    for (int ks = 0; ks < 4; ++ks) {
        int kt = ks * 32;
        bf16x8 a[2], bf[4];
        #pragma unroll
        for (int m = 0; m < 2; ++m) {
            int l = lbase + m * 16 + l15;
            a[m] = *(const bf16x8*)&timef[((size_t)l * NH + h) * TF + kt + lk * 8];
        }
        #pragma unroll
        for (int n = 0; n < 4; ++n)
            bf[n] = *(const bf16x8*)&wt[(size_t)(n * 16 + l15) * TF + kt + lk * 8];
        #pragma unroll
        for (int m = 0; m < 2; ++m)
            #pragma unroll
            for (int n = 0; n < 4; ++n)
                acc[m][n] = __builtin_amdgcn_mfma_f32_16x16x32_bf16(a[m], bf[n], acc[m][n], 0, 0, 0);
    }

    #pragma unroll
    for (int m = 0; m < 2; ++m) {
        #pragma unroll
        for (int r = 0; r < 4; ++r) {
            int l = lbase + m * 16 + lk * 4 + r;
            int row = b * LSEQ + l;
            float q = qs[(size_t)row * NH + h] * mask[row];
            #pragma unroll
            for (int n = 0; n < 4; ++n) {
                int hd = n * 16 + l15;
                comb[(size_t)row * DIM + h * HDIM + hd] =
                    __float2bfloat16(q * acc[m][n][r]);
            }
        }
    }
}

// ---------------- LayerNorm over last dim (512) ----------------
// OUTBF=1: write bf16 only (LN1 -> interb); OUTBF=0: write f32 only (LN2 -> out)
template<int OUTBF>
__global__ __launch_bounds__(256) void ln_kernel(const float* __restrict__ X,
                                                 const float* __restrict__ g,
                                                 const float* __restrict__ bta,
                                                 float* __restrict__ outf,
                                                 bf16* __restrict__ outb)
{
    int row = blockIdx.x;
    const float* x = X + (size_t)row * DIM;
    float v0 = x[threadIdx.x], v1 = x[threadIdx.x + 256];
    float s = v0 + v1, s2 = v0 * v0 + v1 * v1;
    #pragma unroll
    for (int off = 1; off < 64; off <<= 1) {
        s  += __shfl_xor(s,  off);
        s2 += __shfl_xor(s2, off);
    }
    __shared__ float sh[2][4];
    int wave = threadIdx.x >> 6, lane = threadIdx.x & 63;
    if (lane == 0) { sh[0][wave] = s; sh[1][wave] = s2; }
    __syncthreads();
    s  = sh[0][0] + sh[0][1] + sh[0][2] + sh[0][3];
    s2 = sh[1][0] + sh[1][1] + sh[1][2] + sh[1][3];
    float mu  = s * (1.0f / DIM);
    float var = s2 * (1.0f / DIM) - mu * mu;
    float inv = rsqrtf(var + 1e-5f);
    int c0 = threadIdx.x, c1 = threadIdx.x + 256;
    float o0 = (v0 - mu) * inv * g[c0] + bta[c0];
    float o1 = (v1 - mu) * inv * g[c1] + bta[c1];
    if constexpr (OUTBF) {
        outb[(size_t)row * DIM + c0] = __float2bfloat16(o0);
        outb[(size_t)row * DIM + c1] = __float2bfloat16(o1);
    } else {
        outf[(size_t)row * DIM + c0] = o0;
        outf[(size_t)row * DIM + c1] = o1;
    }
}

extern "C" void kernel_launch(void* const* d_in, const int* in_sizes, int n_in,
                              void* d_out, int out_size, void* d_ws, size_t ws_size,
                              hipStream_t stream)
{
    const float* tensor = (const float*)d_in[0];
    const float* mask   = (const float*)d_in[1];
    const float* tang   = (const float*)d_in[2];
    const float* htd    = (const float*)d_in[3];
    const float* Qw     = (const float*)d_in[4];
    const float* qb     = (const float*)d_in[5];
    // d_in[6], d_in[7] (Kw, Kb) dead code
    const float* Vw     = (const float*)d_in[8];
    const float* Vb     = (const float*)d_in[9];
    const float* Ow     = (const float*)d_in[10];
    const float* Ob     = (const float*)d_in[11];
    const float* g1     = (const float*)d_in[12];
    const float* b1     = (const float*)d_in[13];
    const float* Win    = (const float*)d_in[14];
    const float* bin    = (const float*)d_in[15];
    const float* Wout   = (const float*)d_in[16];
    const float* bout   = (const float*)d_in[17];
    const float* g2     = (const float*)d_in[18];
    const float* b2     = (const float*)d_in[19];
    float* out = (float*)d_out;

    float* ws = (float*)d_ws;
    // f32-unit offsets. Steps: s1 setup, s2 qv, s3 wpart, s4 wred, s5 comb,
    // s6 O, s7 LN1, s8 ffn1, s9 ffn2, s10 LN2. Lifetimes (write -> last read):
    //   vT      [0,        1048576)  bf16 [512][4096]: s2->s3
    //   actb    [0,        3145728)  bf16 FFN act: s8->s9
    //   tensorb [1048576,  2097152)  s1->s2; combb reuse: s5->s6
    //   timefb  [2097152,  3145728)  s1->s5
    //   timefT  [3145728,  4194304)  s1->s3; interb reuse: s7->s9 (FFN1 A + FFN2 res)
    //   wpart   [4194304,  8388608)  s3->s4
    //   preLN1  [4194304,  6291456)  reuse: s6->s7
    //   buf5    [6291456,  8388608)  preLN2 reuse: s9->s10
    //   WTb     [8388608,  8454144)  bf16: s4->s5
    //   qs      [8454144,  8486912)  f32:  s2->s5
    //   QVwT    [8486912,  8749056)  bf16 [1024][512]: s1->s2
    //   OwT     [8749056,  8880128)  s1->s6
    //   WinT    [8880128,  9273344)  s1->s8
    //   WoutT   [9273344,  9666560)  s1->s9
    // peak = 9666560 f32 = 38.7 MB (< 47.2 MB proven)
    bf16*  vT     = (bf16*)(ws + 0);
    bf16*  actb   = (bf16*)(ws + 0);
    bf16*  tensorb= (bf16*)(ws + 1048576);
    bf16*  combb  = tensorb;
    bf16*  timefb = (bf16*)(ws + 2097152);
    bf16*  timefT = (bf16*)(ws + 3145728);
    bf16*  interb = (bf16*)(ws + 3145728);
    float* wpart  = ws + 4194304;
    float* preLN1 = ws + 4194304;
    float* buf5   = ws + 6291456;
    bf16*  WTb    = (bf16*)(ws + 8388608);
    float* qs     = ws + 8454144;
    bf16*  QVwT   = (bf16*)(ws + 8486912);
    bf16*  QwT    = QVwT;                         // rows 0..511
    bf16*  VwT    = QVwT + (size_t)512 * 512;     // rows 512..1023
    bf16*  OwT    = (bf16*)(ws + 8749056);
    bf16*  WinT   = (bf16*)(ws + 8880128);
    bf16*  WoutT  = (bf16*)(ws + 9273344);

    // 1. setup: tensor->bf16 + timef/timefT (single sincos pass) + weight transposes
    setup_kernel<<<5376, 256, 0, stream>>>(tensor, tang, htd, Qw, Vw, Ow, Win, Wout,
                                           tensorb, timefb, timefT, QwT, VwT, OwT, WinT, WoutT);
    // 2. fused Q+V GEMM (64x128, 512 blocks): qs row-sums + vT bf16 (coalesced)
    gemm_qv<<<dim3(8, 64), 256, 0, stream>>>(tensorb, QVwT, qb, Vb, qs, vT);
    // 3. WT partials via MFMA (split-K 32, 512 blocks)
    wpart_mfma<<<dim3(16, KCH), 256, 0, stream>>>(timefT, vT, wpart);
    // 4. reduce -> WT bf16
    wred_kernel<<<512, 256, 0, stream>>>(wpart, WTb);
    // 5. comb via MFMA (256 blocks)
    comb_mfma<<<dim3(16, 16), 256, 0, stream>>>(timefb, WTb, qs, mask, combb);
    // 6. attn_out + residual(tensor) -> preLN1  (64x64, 512 blocks)
    gemm_big<64, 64, 2, float, float><<<dim3(8, 64), 256, 0, stream>>>(combb, OwT, Ob, tensor, preLN1, ROWS, DIM, DIM);
    // 7. LN1 -> interb bf16 only
    ln_kernel<1><<<ROWS, 256, 0, stream>>>(preLN1, g1, b1, nullptr, interb);
    // 8. FFN in + gelu -> bf16  (64x128, 768 blocks)
    gemm_big<64, 128, 3, bf16, float><<<dim3(12, 64), 256, 0, stream>>>(interb, WinT, bin, nullptr, actb, ROWS, LIND, DIM);
    // 9. FFN out + residual(interb bf16)  (64x64, 512 blocks)
    gemm_big<64, 64, 4, float, bf16><<<dim3(8, 64), 256, 0, stream>>>(actb, WoutT, bout, interb, buf5, ROWS, DIM, LIND);
    // 10. LN2 -> f32 output
    ln_kernel<0><<<ROWS, 256, 0, stream>>>(buf5, g2, b2, out, nullptr);
}

// Round 13
// 97.342 us; speedup vs baseline: 1.4473x; 1.0148x over previous
//
#include <hip/hip_runtime.h>
#include <hip/hip_bf16.h>

typedef __hip_bfloat16 bf16;
typedef __attribute__((ext_vector_type(8))) __bf16 bf16x8;
typedef __attribute__((ext_vector_type(4))) float f32x4;

#define DIM   512
#define NH    8
#define HDIM  64
#define LIND  1536
#define LSEQ  2048
#define ROWS  4096        // B*L
#define TF    128         // time features
#define KCH   32          // wpart split-K chunks (BK=64 each)

__device__ __forceinline__ float b2f(bf16 v){ return __bfloat162float(v); }
__device__ __forceinline__ void stc(float* C, size_t i, float v){ C[i] = v; }
__device__ __forceinline__ void stc(bf16*  C, size_t i, float v){ C[i] = __float2bfloat16(v); }
__device__ __forceinline__ float ldr(const float* p, size_t i){ return p[i]; }
__device__ __forceinline__ float ldr(const bf16*  p, size_t i){ return b2f(p[i]); }

typedef const __attribute__((address_space(1))) unsigned int* gp1_t;
typedef __attribute__((address_space(3))) unsigned int* lp3_t;
__device__ __forceinline__ void gload16(const bf16* g, unsigned short* l) {
    __builtin_amdgcn_global_load_lds((gp1_t)(const void*)g, (lp3_t)(void*)l, 16, 0, 0);
}

// ---------- setup: tensor->bf16 | time (both layouts, 1 sincos) | transposes ----
__global__ __launch_bounds__(256) void setup_kernel(const float* __restrict__ tensor,
                                                    const float* __restrict__ tang,
                                                    const float* __restrict__ htd,
                                                    const float* __restrict__ Qw,
                                                    const float* __restrict__ Vw,
                                                    const float* __restrict__ Ow,
                                                    const float* __restrict__ Win,
                                                    const float* __restrict__ Wout,
                                                    bf16* __restrict__ tensorb,
                                                    bf16* __restrict__ timef,
                                                    bf16* __restrict__ timefT,
                                                    bf16* __restrict__ QwT,
                                                    bf16* __restrict__ VwT,
                                                    bf16* __restrict__ OwT,
                                                    bf16* __restrict__ WinT,
                                                    bf16* __restrict__ WoutT)
{
    __shared__ unsigned short st0[32][33];
    __shared__ unsigned short st1[32][33];
    __shared__ float t[32][33];

    int id = blockIdx.x;
    if (id < 2048) {
        int i = id * 256 + threadIdx.x;
        float4 v = ((const float4*)tensor)[i];
        bf16 tt[4];
        tt[0] = __float2bfloat16(v.x); tt[1] = __float2bfloat16(v.y);
        tt[2] = __float2bfloat16(v.z); tt[3] = __float2bfloat16(v.w);
        *(uint2*)&tensorb[(size_t)i * 4] = *(uint2*)tt;
        return;
    }
    if (id < 3072) {
        int q = id - 2048;              // 0..1023
        int h = q >> 7;                 // 8
        int dblk = (q >> 6) & 1;        // 2
        int lblk = q & 63;              // 64
        int d0 = dblk * 32, l0 = lblk * 32;
        int x = threadIdx.x & 31, y = threadIdx.x >> 5;
        float ta = tang[h * 64 + d0 + x];
        float hb = htd[h];
        #pragma unroll
        for (int r = 0; r < 4; ++r) {
            int ll = y + 8 * r;
            float ang = ((float)(l0 + ll) + hb) * ta;
            float s, c;
            sincosf(ang, &s, &c);
            bf16 v0 = __float2bfloat16((c + s) * 0.125f);
            bf16 v1 = __float2bfloat16((c - s) * 0.125f);
            bf16* p = timef + ((size_t)(l0 + ll) * NH + h) * TF;
            p[d0 + x]      = v0;
            p[d0 + x + 64] = v1;
            st0[x][ll] = *(unsigned short*)&v0;
            st1[x][ll] = *(unsigned short*)&v1;
        }
        __syncthreads();
        #pragma unroll
        for (int r = 0; r < 4; ++r) {
            int dd = y + 8 * r;
            unsigned short u0 = st0[dd][x], u1 = st1[dd][x];
            timefT[((size_t)(h * 128 + d0 + dd)) * LSEQ + l0 + x]      = *(bf16*)&u0;
            timefT[((size_t)(h * 128 + d0 + dd + 64)) * LSEQ + l0 + x] = *(bf16*)&u1;
        }
        return;
    }
    id -= 3072;
    const float* in; bf16* out; int R, C, tx, ty;
    if (id < 256)        { in = Qw;   out = QwT;   R = 512;  C = 512;  tx = id & 15; ty = id >> 4; }
    else if (id < 512)   { id -= 256;  in = Vw;   out = VwT;   R = 512;  C = 512;  tx = id & 15; ty = id >> 4; }
    else if (id < 768)   { id -= 512;  in = Ow;   out = OwT;   R = 512;  C = 512;  tx = id & 15; ty = id >> 4; }
    else if (id < 1536)  { id -= 768;  in = Win;  out = WinT;  R = 512;  C = 1536; tx = id % 48; ty = id / 48; }
    else                 { id -= 1536; in = Wout; out = WoutT; R = 1536; C = 512;  tx = id & 15; ty = id >> 4; }

    int bx = tx * 32, by = ty * 32;
    int x = threadIdx.x & 31, y = threadIdx.x >> 5;
    #pragma unroll
    for (int r = 0; r < 32; r += 8)
        t[y + r][x] = in[(size_t)(by + y + r) * C + bx + x];
    __syncthreads();
    #pragma unroll
    for (int r = 0; r < 32; r += 8)
        out[(size_t)(bx + y + r) * R + by + x] = __float2bfloat16(t[x][y + r]);
}

// ===== double-buffered MFMA GEMM, templated BK (both-sides XOR swizzle) =====
// LDS row = BK bf16; staging slot e: row=e/GR, granule g=e%GR holds global
// granule g^(row&(GR-1)); reads XOR identically (2-way alias = free).
// EPI: 2 = x+b+res (O)   3 = gelu(x+b) (FFN1)   4 = x+b+res (FFN2, bf16 res)
template<int BM, int BN, int BK, int EPI, typename OUTT, typename REST>
__global__ __launch_bounds__(256) void gemm_big(const bf16* __restrict__ A,
                                                const bf16* __restrict__ Bt,
                                                const float* __restrict__ bias,
                                                const REST* __restrict__ res,
                                                OUTT* __restrict__ C,
                                                int M, int N, int K)
{
    constexpr int RM = BM / 32, RN = BN / 32;
    constexpr int GR = BK / 8;                 // granules per row
    constexpr int ITA = BM * GR / 256, ITB = BN * GR / 256;
    __shared__ unsigned short As[2][BM * BK];
    __shared__ unsigned short Bs[2][BN * BK];

    int tid  = threadIdx.x;
    int lane = tid & 63, wave = tid >> 6;
    int wr = wave >> 1, wc = wave & 1;
    int bm = blockIdx.y * BM, bn = blockIdx.x * BN;
    int l15 = lane & 15, lk = lane >> 4;

    const bf16* gA[ITA]; const bf16* gB[ITB];
    #pragma unroll
    for (int it = 0; it < ITA; ++it) {
        int e = it * 256 + tid, row = e / GR, g = e % GR;
        gA[it] = &A[(size_t)(bm + row) * K + (g ^ (row & (GR - 1))) * 8];
    }
    #pragma unroll
    for (int it = 0; it < ITB; ++it) {
        int e = it * 256 + tid, row = e / GR, g = e % GR;
        gB[it] = &Bt[(size_t)(bn + row) * K + (g ^ (row & (GR - 1))) * 8];
    }

    f32x4 acc[RM][RN] = {};
    int NT = K / BK;

    #pragma unroll
    for (int it = 0; it < ITA; ++it) gload16(gA[it], &As[0][(it * 256 + tid) * 8]);
    #pragma unroll
    for (int it = 0; it < ITB; ++it) gload16(gB[it], &Bs[0][(it * 256 + tid) * 8]);
    __syncthreads();

    for (int t = 0; t < NT; ++t) {
        int cur = t & 1;
        if (t + 1 < NT) {
            #pragma unroll
            for (int it = 0; it < ITA; ++it)
                gload16(gA[it] + (t + 1) * BK, &As[cur ^ 1][(it * 256 + tid) * 8]);
            #pragma unroll
            for (int it = 0; it < ITB; ++it)
                gload16(gB[it] + (t + 1) * BK, &Bs[cur ^ 1][(it * 256 + tid) * 8]);
        }
        #pragma unroll
        for (int s = 0; s < BK / 32; ++s) {
            bf16x8 a[RM], b[RN];
            int g8 = ((s * 4 + lk) ^ (l15 & (GR - 1))) * 8;
            #pragma unroll
            for (int m = 0; m < RM; ++m) {
                int row = wr * (BM / 2) + m * 16 + l15;
                a[m] = *(const bf16x8*)&As[cur][row * BK + g8];
            }
            #pragma unroll
            for (int n = 0; n < RN; ++n) {
                int row = wc * (BN / 2) + n * 16 + l15;
                b[n] = *(const bf16x8*)&Bs[cur][row * BK + g8];
            }
            #pragma unroll
            for (int m = 0; m < RM; ++m)
                #pragma unroll
                for (int n = 0; n < RN; ++n)
                    acc[m][n] = __builtin_amdgcn_mfma_f32_16x16x32_bf16(a[m], b[n], acc[m][n], 0, 0, 0);
        }
        __syncthreads();
    }

    #pragma unroll
    for (int m = 0; m < RM; ++m) {
        #pragma unroll
        for (int n = 0; n < RN; ++n) {
            int gcol = bn + wc * (BN / 2) + n * 16 + l15;
            float bs = bias[gcol];
            #pragma unroll
            for (int r = 0; r < 4; ++r) {
                int grow = bm + wr * (BM / 2) + m * 16 + lk * 4 + r;
                float x = acc[m][n][r];
                float o;
                if constexpr (EPI == 2) {
                    o = x + bs + ldr(res, (size_t)grow * N + gcol);
                } else if constexpr (EPI == 3) {
                    float t = x + bs;
                    float u = t + 0.044715f * t * t * t;
                    o = 0.5f * t * (1.0f + tanhf(0.7978845608028654f * u));
                } else {
                    o = x + bs + ldr(res, (size_t)grow * N + gcol);
                }
                stc(C, (size_t)grow * N + gcol, o);
            }
        }
    }
}

// ----- fused Q+V GEMM, BM=64 BN=128 BK=64: Bt = [QwT;VwT] (1024x512) -----
__global__ __launch_bounds__(256) void gemm_qv(const bf16* __restrict__ A,
                                               const bf16* __restrict__ Bt,
                                               const float* __restrict__ qb,
                                               const float* __restrict__ Vb,
                                               float* __restrict__ qs,
                                               bf16* __restrict__ vT)
{
    constexpr int BM = 64, BN = 128, RM = 2, RN = 4;
    __shared__ unsigned short As[2][BM * 64];
    __shared__ unsigned short Bs[2][BN * 64];
    __shared__ float qsums[2][64];

    const int K = DIM;
    int tid  = threadIdx.x;
    int lane = tid & 63, wave = tid >> 6;
    int wr = wave >> 1, wc = wave & 1;
    int bm = blockIdx.y * BM, bn = blockIdx.x * BN;
    int l15 = lane & 15, lk = lane >> 4;

    const bf16* gA[2]; const bf16* gB[4];
    #pragma unroll
    for (int it = 0; it < 2; ++it) {
        int e = it * 256 + tid, row = e >> 3, g = e & 7;
        gA[it] = &A[(size_t)(bm + row) * K + (g ^ (row & 7)) * 8];
    }
    #pragma unroll
    for (int it = 0; it < 4; ++it) {
        int e = it * 256 + tid, row = e >> 3, g = e & 7;
        gB[it] = &Bt[(size_t)(bn + row) * K + (g ^ (row & 7)) * 8];
    }

    f32x4 acc[RM][RN] = {};
    const int NT = K >> 6;   // 8

    #pragma unroll
    for (int it = 0; it < 2; ++it) gload16(gA[it], &As[0][(it * 256 + tid) * 8]);
    #pragma unroll
    for (int it = 0; it < 4; ++it) gload16(gB[it], &Bs[0][(it * 256 + tid) * 8]);
    __syncthreads();

    for (int t = 0; t < NT; ++t) {
        int cur = t & 1;
        if (t + 1 < NT) {
            #pragma unroll
            for (int it = 0; it < 2; ++it)
                gload16(gA[it] + (t + 1) * 64, &As[cur ^ 1][(it * 256 + tid) * 8]);
            #pragma unroll
            for (int it = 0; it < 4; ++it)
                gload16(gB[it] + (t + 1) * 64, &Bs[cur ^ 1][(it * 256 + tid) * 8]);
        }
        #pragma unroll
        for (int s = 0; s < 2; ++s) {
            bf16x8 a[RM], b[RN];
            int g8 = ((s * 4 + lk) ^ (l15 & 7)) * 8;
            #pragma unroll
            for (int m = 0; m < RM; ++m) {
                int row = wr * 32 + m * 16 + l15;
                a[m] = *(const bf16x8*)&As[cur][row * 64 + g8];
            }
            #pragma unroll
            for (int n = 0; n < RN; ++n) {
                int row = wc * 64 + n * 16 + l15;
                b[n] = *(const bf16x8*)&Bs[cur][row * 64 + g8];
            }
            #pragma unroll
            for (int m = 0; m < RM; ++m)
                #pragma unroll
                for (int n = 0; n < RN; ++n)
                    acc[m][n] = __builtin_amdgcn_mfma_f32_16x16x32_bf16(a[m], b[n], acc[m][n], 0, 0, 0);
        }
        __syncthreads();
    }

    if (bn < DIM) {
        float eq[RN];
        #pragma unroll
        for (int n = 0; n < RN; ++n)
            eq[n] = expf(qb[bn + wc * 64 + n * 16 + l15]);
        #pragma unroll
        for (int m = 0; m < RM; ++m) {
            #pragma unroll
            for (int r = 0; r < 4; ++r) {
                float s = 0.f;
                #pragma unroll
                for (int n = 0; n < RN; ++n) {
                    float x = acc[m][n][r] - eq[n];
                    s += 1.0f / (1.0f + expf(-x));
                }
                s *= (1.0f / 64.0f);
                #pragma unroll
                for (int off = 1; off < 16; off <<= 1) s += __shfl_xor(s, off);
                if (l15 == 0)
                    qsums[wc][wr * 32 + m * 16 + lk * 4 + r] = s;
            }
        }
        __syncthreads();
        if (tid < 128) {
            int hh = tid >> 6, row = tid & 63;
            qs[(size_t)(bm + row) * NH + (bn >> 6) + hh] = qsums[hh][row];
        }
    } else {
        // V -> vT[col][t] via LDS transpose (Bs dead after last barrier)
        unsigned short* tb = &Bs[0][0];        // [128 col][72 t-pad]
        #pragma unroll
        for (int m = 0; m < RM; ++m) {
            int trow0 = wr * 32 + m * 16 + lk * 4;
            #pragma unroll
            for (int n = 0; n < RN; ++n) {
                int col = wc * 64 + n * 16 + l15;
                float bs = Vb[bn - DIM + col];
                bf16 tmp[4];
                #pragma unroll
                for (int r = 0; r < 4; ++r)
                    tmp[r] = __float2bfloat16(acc[m][n][r] + bs);
                *(uint2*)&tb[col * 72 + trow0] = *(uint2*)tmp;
            }
        }
        __syncthreads();
        #pragma unroll
        for (int rep = 0; rep < 8; ++rep) {
            int idx = rep * 256 + tid;        // < 2048
            int col = idx >> 4;               // 0..127
            int t4  = (idx & 15) * 4;         // 0..60
            uint2 v = *(uint2*)&tb[col * 72 + t4];
            *(uint2*)&vT[(size_t)(bn - DIM + col) * ROWS + bm + t4] = v;
        }
    }
}

// ---- wpart_mfma: per (bh, kc) one BK=64 t-slab; partials stored bf16 ----
__global__ __launch_bounds__(256) void wpart_mfma(const bf16* __restrict__ timefT,
                                                  const bf16* __restrict__ vT,
                                                  bf16* __restrict__ wpart)
{
    __shared__ unsigned short As[128 * 64];
    __shared__ unsigned short Bs[64 * 64];

    int bh = blockIdx.x;              // 0..15
    int kc = blockIdx.y;              // 0..31
    int b = bh >> 3, h = bh & 7;
    int tid  = threadIdx.x;
    int lane = tid & 63, wave = tid >> 6;
    int wr = wave >> 1, wc = wave & 1;
    int l15 = lane & 15, lk = lane >> 4;
    int k0 = kc * 64;

    const bf16* Abase = timefT + (size_t)h * (128 * LSEQ) + k0;
    const bf16* Bbase = vT + (size_t)h * 64 * ROWS + (size_t)b * LSEQ + k0;

    #pragma unroll
    for (int it = 0; it < 4; ++it) {
        int e = it * 256 + tid, row = e >> 3, g = e & 7;
        gload16(Abase + (size_t)row * LSEQ + (g ^ (row & 7)) * 8, &As[e * 8]);
    }
    #pragma unroll
    for (int it = 0; it < 2; ++it) {
        int e = it * 256 + tid, row = e >> 3, g = e & 7;
        gload16(Bbase + (size_t)row * ROWS + (g ^ (row & 7)) * 8, &Bs[e * 8]);
    }
    __syncthreads();

    f32x4 acc[4][2] = {};
    #pragma unroll
    for (int s = 0; s < 2; ++s) {
        bf16x8 a[4], bv[2];
        int g8 = ((s * 4 + lk) ^ (l15 & 7)) * 8;
        #pragma unroll
        for (int m = 0; m < 4; ++m) {
            int row = wr * 64 + m * 16 + l15;
            a[m] = *(const bf16x8*)&As[row * 64 + g8];
        }
        #pragma unroll
        for (int n = 0; n < 2; ++n) {
            int row = wc * 32 + n * 16 + l15;
            bv[n] = *(const bf16x8*)&Bs[row * 64 + g8];
        }
        #pragma unroll
        for (int m = 0; m < 4; ++m)
            #pragma unroll
            for (int n = 0; n < 2; ++n)
                acc[m][n] = __builtin_amdgcn_mfma_f32_16x16x32_bf16(a[m], bv[n], acc[m][n], 0, 0, 0);
    }

    bf16* wp = wpart + ((size_t)(kc * 16 + bh)) * (HDIM * TF);
    #pragma unroll
    for (int m = 0; m < 4; ++m) {
        int gd0 = wr * 64 + m * 16 + lk * 4;
        #pragma unroll
        for (int n = 0; n < 2; ++n) {
            int ghd = wc * 32 + n * 16 + l15;
            bf16 tmp[4];
            #pragma unroll
            for (int r = 0; r < 4; ++r) tmp[r] = __float2bfloat16(acc[m][n][r]);
            *(uint2*)&wp[ghd * TF + gd0] = *(uint2*)tmp;
        }
    }
}

// ---- wred: sum 32 bf16 partials -> WT bf16, 4 elems/thread ----
__global__ __launch_bounds__(256) void wred_kernel(const bf16* __restrict__ wpart,
                                                   bf16* __restrict__ WT)
{
    int i4 = (blockIdx.x * 256 + threadIdx.x) * 4;   // < 131072
    float s[4] = {};
    #pragma unroll
    for (int kc = 0; kc < KCH; ++kc) {
        uint2 u = *(const uint2*)&wpart[(size_t)kc * 131072 + i4];
        const bf16* p = (const bf16*)&u;
        #pragma unroll
        for (int r = 0; r < 4; ++r) s[r] += b2f(p[r]);
    }
    bf16 o[4];
    #pragma unroll
    for (int r = 0; r < 4; ++r) o[r] = __float2bfloat16(s[r]);
    *(uint2*)&WT[i4] = *(uint2*)o;
}

// ---- comb[b,l,h,:] = qs[l,h]*mask[l] * (time[l,h,:] @ WT[bh]^T), MFMA ------
// grid (16 bh, 32 lt); 4 waves x 16 l-rows; 512 blocks = 2/CU
__global__ __launch_bounds__(256) void comb_mfma(const bf16* __restrict__ timef,
                                                 const bf16* __restrict__ WT,
                                                 const float* __restrict__ qs,
                                                 const float* __restrict__ mask,
                                                 bf16* __restrict__ comb)
{
    int bh = blockIdx.x;
    int b = bh >> 3, h = bh & 7;
    int lane = threadIdx.x & 63, wave = threadIdx.x >> 6;
    int l15 = lane & 15, lk = lane >> 4;
    int lbase = blockIdx.y * 64 + wave * 16;

    const bf16* wt = WT + (size_t)bh * (HDIM * TF);

    f32x4 acc[4] = {};
    #pragma unroll
    for (int ks = 0; ks < 4; ++ks) {
        int kt = ks * 32;
        bf16x8 a, bf[4];
        a = *(const bf16x8*)&timef[((size_t)(lbase + l15) * NH + h) * TF + kt + lk * 8];
        #pragma unroll
        for (int n = 0; n < 4; ++n)
            bf[n] = *(const bf16x8*)&wt[(size_t)(n * 16 + l15) * TF + kt + lk * 8];
        #pragma unroll
        for (int n = 0; n < 4; ++n)
            acc[n] = __builtin_amdgcn_mfma_f32_16x16x32_bf16(a, bf[n], acc[n], 0, 0, 0);
    }

    #pragma unroll
    for (int r = 0; r < 4; ++r) {
        int l = lbase + lk * 4 + r;
        int row = b * LSEQ + l;
        float q = qs[(size_t)row * NH + h] * mask[row];
        #pragma unroll
        for (int n = 0; n < 4; ++n) {
            int hd = n * 16 + l15;
            comb[(size_t)row * DIM + h * HDIM + hd] = __float2bfloat16(q * acc[n][r]);
        }
    }
}

// ---------------- LayerNorm over last dim (512) ----------------
template<int OUTBF>
__global__ __launch_bounds__(256) void ln_kernel(const float* __restrict__ X,
                                                 const float* __restrict__ g,
                                                 const float* __restrict__ bta,
                                                 float* __restrict__ outf,
                                                 bf16* __restrict__ outb)
{
    int row = blockIdx.x;
    const float* x = X + (size_t)row * DIM;
    float v0 = x[threadIdx.x], v1 = x[threadIdx.x + 256];
    float s = v0 + v1, s2 = v0 * v0 + v1 * v1;
    #pragma unroll
    for (int off = 1; off < 64; off <<= 1) {
        s  += __shfl_xor(s,  off);
        s2 += __shfl_xor(s2, off);
    }
    __shared__ float sh[2][4];
    int wave = threadIdx.x >> 6, lane = threadIdx.x & 63;
    if (lane == 0) { sh[0][wave] = s; sh[1][wave] = s2; }
    __syncthreads();
    s  = sh[0][0] + sh[0][1] + sh[0][2] + sh[0][3];
    s2 = sh[1][0] + sh[1][1] + sh[1][2] + sh[1][3];
    float mu  = s * (1.0f / DIM);
    float var = s2 * (1.0f / DIM) - mu * mu;
    float inv = rsqrtf(var + 1e-5f);
    int c0 = threadIdx.x, c1 = threadIdx.x + 256;
    float o0 = (v0 - mu) * inv * g[c0] + bta[c0];
    float o1 = (v1 - mu) * inv * g[c1] + bta[c1];
    if constexpr (OUTBF) {
        outb[(size_t)row * DIM + c0] = __float2bfloat16(o0);
        outb[(size_t)row * DIM + c1] = __float2bfloat16(o1);
    } else {
        outf[(size_t)row * DIM + c0] = o0;
        outf[(size_t)row * DIM + c1] = o1;
    }
}

extern "C" void kernel_launch(void* const* d_in, const int* in_sizes, int n_in,
                              void* d_out, int out_size, void* d_ws, size_t ws_size,
                              hipStream_t stream)
{
    const float* tensor = (const float*)d_in[0];
    const float* mask   = (const float*)d_in[1];
    const float* tang   = (const float*)d_in[2];
    const float* htd    = (const float*)d_in[3];
    const float* Qw     = (const float*)d_in[4];
    const float* qb     = (const float*)d_in[5];
    // d_in[6], d_in[7] (Kw, Kb) dead code
    const float* Vw     = (const float*)d_in[8];
    const float* Vb     = (const float*)d_in[9];
    const float* Ow     = (const float*)d_in[10];
    const float* Ob     = (const float*)d_in[11];
    const float* g1     = (const float*)d_in[12];
    const float* b1     = (const float*)d_in[13];
    const float* Win    = (const float*)d_in[14];
    const float* bin    = (const float*)d_in[15];
    const float* Wout   = (const float*)d_in[16];
    const float* bout   = (const float*)d_in[17];
    const float* g2     = (const float*)d_in[18];
    const float* b2     = (const float*)d_in[19];
    float* out = (float*)d_out;

    float* ws = (float*)d_ws;
    // Layout identical to round 12 (wpart now bf16, occupies first half of its region):
    bf16*  vT     = (bf16*)(ws + 0);
    bf16*  actb   = (bf16*)(ws + 0);
    bf16*  tensorb= (bf16*)(ws + 1048576);
    bf16*  combb  = tensorb;
    bf16*  timefb = (bf16*)(ws + 2097152);
    bf16*  timefT = (bf16*)(ws + 3145728);
    bf16*  interb = (bf16*)(ws + 3145728);
    bf16*  wpart  = (bf16*)(ws + 4194304);    // 32 x 131072 bf16 = 8 MB
    float* preLN1 = ws + 4194304;
    float* buf5   = ws + 6291456;
    bf16*  WTb    = (bf16*)(ws + 8388608);
    float* qs     = ws + 8454144;
    bf16*  QVwT   = (bf16*)(ws + 8486912);
    bf16*  QwT    = QVwT;
    bf16*  VwT    = QVwT + (size_t)512 * 512;
    bf16*  OwT    = (bf16*)(ws + 8749056);
    bf16*  WinT   = (bf16*)(ws + 8880128);
    bf16*  WoutT  = (bf16*)(ws + 9273344);

    // 1. setup
    setup_kernel<<<5376, 256, 0, stream>>>(tensor, tang, htd, Qw, Vw, Ow, Win, Wout,
                                           tensorb, timefb, timefT, QwT, VwT, OwT, WinT, WoutT);
    // 2. fused Q+V GEMM (64x128, BK=64, 512 blocks)
    gemm_qv<<<dim3(8, 64), 256, 0, stream>>>(tensorb, QVwT, qb, Vb, qs, vT);
    // 3. WT partials via MFMA (split-K 32, bf16 partials)
    wpart_mfma<<<dim3(16, KCH), 256, 0, stream>>>(timefT, vT, wpart);
    // 4. reduce -> WT bf16 (4 elems/thread)
    wred_kernel<<<128, 256, 0, stream>>>(wpart, WTb);
    // 5. comb via MFMA (512 blocks)
    comb_mfma<<<dim3(16, 32), 256, 0, stream>>>(timefb, WTb, qs, mask, combb);
    // 6. attn_out + residual(tensor) -> preLN1  (64x64, BK=128, 512 blocks)
    gemm_big<64, 64, 128, 2, float, float><<<dim3(8, 64), 256, 0, stream>>>(combb, OwT, Ob, tensor, preLN1, ROWS, DIM, DIM);
    // 7. LN1 -> interb bf16
    ln_kernel<1><<<ROWS, 256, 0, stream>>>(preLN1, g1, b1, nullptr, interb);
    // 8. FFN in + gelu -> bf16  (64x128, BK=64, 768 blocks)
    gemm_big<64, 128, 64, 3, bf16, float><<<dim3(12, 64), 256, 0, stream>>>(interb, WinT, bin, nullptr, actb, ROWS, LIND, DIM);
    // 9. FFN out + residual(interb)  (64x64, BK=128, 512 blocks)
    gemm_big<64, 64, 128, 4, float, bf16><<<dim3(8, 64), 256, 0, stream>>>(actb, WoutT, bout, interb, buf5, ROWS, DIM, LIND);
    // 10. LN2 -> f32 output
    ln_kernel<0><<<ROWS, 256, 0, stream>>>(buf5, g2, b2, out, nullptr);
}

// Round 15
// 96.728 us; speedup vs baseline: 1.4565x; 1.0063x over previous
//
#include <hip/hip_runtime.h>
#include <hip/hip_bf16.h>

typedef __hip_bfloat16 bf16;
typedef __attribute__((ext_vector_type(8))) __bf16 bf16x8;
typedef __attribute__((ext_vector_type(4))) float f32x4;

#define DIM   512
#define NH    8
#define HDIM  64
#define LIND  1536
#define LSEQ  2048
#define ROWS  4096        // B*L
#define TF    128         // time features
#define KCH   32          // wpart split-K chunks (BK=64 each)

__device__ __forceinline__ float b2f(bf16 v){ return __bfloat162float(v); }
__device__ __forceinline__ void stc(float* C, size_t i, float v){ C[i] = v; }
__device__ __forceinline__ void stc(bf16*  C, size_t i, float v){ C[i] = __float2bfloat16(v); }
__device__ __forceinline__ float ldr(const float* p, size_t i){ return p[i]; }
__device__ __forceinline__ float ldr(const bf16*  p, size_t i){ return b2f(p[i]); }

typedef const __attribute__((address_space(1))) unsigned int* gp1_t;
typedef __attribute__((address_space(3))) unsigned int* lp3_t;
__device__ __forceinline__ void gload16(const bf16* g, unsigned short* l) {
    __builtin_amdgcn_global_load_lds((gp1_t)(const void*)g, (lp3_t)(void*)l, 16, 0, 0);
}

// ---------- setup: tensor->bf16 | time (both layouts, 1 sincos) | transposes ----
__global__ __launch_bounds__(256) void setup_kernel(const float* __restrict__ tensor,
                                                    const float* __restrict__ tang,
                                                    const float* __restrict__ htd,
                                                    const float* __restrict__ Qw,
                                                    const float* __restrict__ Vw,
                                                    const float* __restrict__ Ow,
                                                    const float* __restrict__ Win,
                                                    const float* __restrict__ Wout,
                                                    bf16* __restrict__ tensorb,
                                                    bf16* __restrict__ timef,
                                                    bf16* __restrict__ timefT,
                                                    bf16* __restrict__ QwT,
                                                    bf16* __restrict__ VwT,
                                                    bf16* __restrict__ OwT,
                                                    bf16* __restrict__ WinT,
                                                    bf16* __restrict__ WoutT)
{
    __shared__ unsigned short st0[32][33];
    __shared__ unsigned short st1[32][33];
    __shared__ float t[32][33];

    int id = blockIdx.x;
    if (id < 2048) {
        int i = id * 256 + threadIdx.x;
        float4 v = ((const float4*)tensor)[i];
        bf16 tt[4];
        tt[0] = __float2bfloat16(v.x); tt[1] = __float2bfloat16(v.y);
        tt[2] = __float2bfloat16(v.z); tt[3] = __float2bfloat16(v.w);
        *(uint2*)&tensorb[(size_t)i * 4] = *(uint2*)tt;
        return;
    }
    if (id < 3072) {
        int q = id - 2048;              // 0..1023
        int h = q >> 7;                 // 8
        int dblk = (q >> 6) & 1;        // 2
        int lblk = q & 63;              // 64
        int d0 = dblk * 32, l0 = lblk * 32;
        int x = threadIdx.x & 31, y = threadIdx.x >> 5;
        float ta = tang[h * 64 + d0 + x];
        float hb = htd[h];
        #pragma unroll
        for (int r = 0; r < 4; ++r) {
            int ll = y + 8 * r;
            float ang = ((float)(l0 + ll) + hb) * ta;
            float s, c;
            sincosf(ang, &s, &c);
            bf16 v0 = __float2bfloat16((c + s) * 0.125f);
            bf16 v1 = __float2bfloat16((c - s) * 0.125f);
            bf16* p = timef + ((size_t)(l0 + ll) * NH + h) * TF;
            p[d0 + x]      = v0;
            p[d0 + x + 64] = v1;
            st0[x][ll] = *(unsigned short*)&v0;
            st1[x][ll] = *(unsigned short*)&v1;
        }
        __syncthreads();
        #pragma unroll
        for (int r = 0; r < 4; ++r) {
            int dd = y + 8 * r;
            unsigned short u0 = st0[dd][x], u1 = st1[dd][x];
            timefT[((size_t)(h * 128 + d0 + dd)) * LSEQ + l0 + x]      = *(bf16*)&u0;
            timefT[((size_t)(h * 128 + d0 + dd + 64)) * LSEQ + l0 + x] = *(bf16*)&u1;
        }
        return;
    }
    id -= 3072;
    const float* in; bf16* out; int R, C, tx, ty;
    if (id < 256)        { in = Qw;   out = QwT;   R = 512;  C = 512;  tx = id & 15; ty = id >> 4; }
    else if (id < 512)   { id -= 256;  in = Vw;   out = VwT;   R = 512;  C = 512;  tx = id & 15; ty = id >> 4; }
    else if (id < 768)   { id -= 512;  in = Ow;   out = OwT;   R = 512;  C = 512;  tx = id & 15; ty = id >> 4; }
    else if (id < 1536)  { id -= 768;  in = Win;  out = WinT;  R = 512;  C = 1536; tx = id % 48; ty = id / 48; }
    else                 { id -= 1536; in = Wout; out = WoutT; R = 1536; C = 512;  tx = id & 15; ty = id >> 4; }

    int bx = tx * 32, by = ty * 32;
    int x = threadIdx.x & 31, y = threadIdx.x >> 5;
    #pragma unroll
    for (int r = 0; r < 32; r += 8)
        t[y + r][x] = in[(size_t)(by + y + r) * C + bx + x];
    __syncthreads();
    #pragma unroll
    for (int r = 0; r < 32; r += 8)
        out[(size_t)(bx + y + r) * R + by + x] = __float2bfloat16(t[x][y + r]);
}

// ===== double-buffered MFMA GEMM, templated BK (both-sides XOR swizzle) =====
// EPI: 2 = x+b+res (O)   3 = gelu(x+b) (FFN1, sigmoid identity)   4 = x+b+res (FFN2)
template<int BM, int BN, int BK, int EPI, typename OUTT, typename REST>
__global__ __launch_bounds__(256) void gemm_big(const bf16* __restrict__ A,
                                                const bf16* __restrict__ Bt,
                                                const float* __restrict__ bias,
                                                const REST* __restrict__ res,
                                                OUTT* __restrict__ C,
                                                int M, int N, int K)
{
    constexpr int RM = BM / 32, RN = BN / 32;
    constexpr int GR = BK / 8;                 // granules per row
    constexpr int ITA = BM * GR / 256, ITB = BN * GR / 256;
    __shared__ unsigned short As[2][BM * BK];
    __shared__ unsigned short Bs[2][BN * BK];

    int tid  = threadIdx.x;
    int lane = tid & 63, wave = tid >> 6;
    int wr = wave >> 1, wc = wave & 1;
    int bm = blockIdx.y * BM, bn = blockIdx.x * BN;
    int l15 = lane & 15, lk = lane >> 4;

    const bf16* gA[ITA]; const bf16* gB[ITB];
    #pragma unroll
    for (int it = 0; it < ITA; ++it) {
        int e = it * 256 + tid, row = e / GR, g = e % GR;
        gA[it] = &A[(size_t)(bm + row) * K + (g ^ (row & (GR - 1))) * 8];
    }
    #pragma unroll
    for (int it = 0; it < ITB; ++it) {
        int e = it * 256 + tid, row = e / GR, g = e % GR;
        gB[it] = &Bt[(size_t)(bn + row) * K + (g ^ (row & (GR - 1))) * 8];
    }

    f32x4 acc[RM][RN] = {};
    int NT = K / BK;

    #pragma unroll
    for (int it = 0; it < ITA; ++it) gload16(gA[it], &As[0][(it * 256 + tid) * 8]);
    #pragma unroll
    for (int it = 0; it < ITB; ++it) gload16(gB[it], &Bs[0][(it * 256 + tid) * 8]);
    __syncthreads();

    for (int t = 0; t < NT; ++t) {
        int cur = t & 1;
        if (t + 1 < NT) {
            #pragma unroll
            for (int it = 0; it < ITA; ++it)
                gload16(gA[it] + (t + 1) * BK, &As[cur ^ 1][(it * 256 + tid) * 8]);
            #pragma unroll
            for (int it = 0; it < ITB; ++it)
                gload16(gB[it] + (t + 1) * BK, &Bs[cur ^ 1][(it * 256 + tid) * 8]);
        }
        #pragma unroll
        for (int s = 0; s < BK / 32; ++s) {
            bf16x8 a[RM], b[RN];
            int g8 = ((s * 4 + lk) ^ (l15 & (GR - 1))) * 8;
            #pragma unroll
            for (int m = 0; m < RM; ++m) {
                int row = wr * (BM / 2) + m * 16 + l15;
                a[m] = *(const bf16x8*)&As[cur][row * BK + g8];
            }
            #pragma unroll
            for (int n = 0; n < RN; ++n) {
                int row = wc * (BN / 2) + n * 16 + l15;
                b[n] = *(const bf16x8*)&Bs[cur][row * BK + g8];
            }
            #pragma unroll
            for (int m = 0; m < RM; ++m)
                #pragma unroll
                for (int n = 0; n < RN; ++n)
                    acc[m][n] = __builtin_amdgcn_mfma_f32_16x16x32_bf16(a[m], b[n], acc[m][n], 0, 0, 0);
        }
        __syncthreads();
    }

    #pragma unroll
    for (int m = 0; m < RM; ++m) {
        #pragma unroll
        for (int n = 0; n < RN; ++n) {
            int gcol = bn + wc * (BN / 2) + n * 16 + l15;
            float bs = bias[gcol];
            #pragma unroll
            for (int r = 0; r < 4; ++r) {
                int grow = bm + wr * (BM / 2) + m * 16 + lk * 4 + r;
                float x = acc[m][n][r];
                float o;
                if constexpr (EPI == 2) {
                    o = x + bs + ldr(res, (size_t)grow * N + gcol);
                } else if constexpr (EPI == 3) {
                    // gelu_tanh(t) == t * sigmoid(2*0.7978845608*(t + 0.044715 t^3))
                    float t = x + bs;
                    float u = 1.5957691216057308f * (t + 0.044715f * t * t * t);
                    o = t / (1.0f + expf(-u));
                } else {
                    o = x + bs + ldr(res, (size_t)grow * N + gcol);
                }
                stc(C, (size_t)grow * N + gcol, o);
            }
        }
    }
}

// ----- fused Q+V GEMM, BM=64 BN=128 BK=64: Bt = [QwT;VwT] (1024x512) -----
__global__ __launch_bounds__(256) void gemm_qv(const bf16* __restrict__ A,
                                               const bf16* __restrict__ Bt,
                                               const float* __restrict__ qb,
                                               const float* __restrict__ Vb,
                                               float* __restrict__ qs,
                                               bf16* __restrict__ vT)
{
    constexpr int BM = 64, BN = 128, RM = 2, RN = 4;
    __shared__ unsigned short As[2][BM * 64];
    __shared__ unsigned short Bs[2][BN * 64];
    __shared__ float qsums[2][64];

    const int K = DIM;
    int tid  = threadIdx.x;
    int lane = tid & 63, wave = tid >> 6;
    int wr = wave >> 1, wc = wave & 1;
    int bm = blockIdx.y * BM, bn = blockIdx.x * BN;
    int l15 = lane & 15, lk = lane >> 4;

    const bf16* gA[2]; const bf16* gB[4];
    #pragma unroll
    for (int it = 0; it < 2; ++it) {
        int e = it * 256 + tid, row = e >> 3, g = e & 7;
        gA[it] = &A[(size_t)(bm + row) * K + (g ^ (row & 7)) * 8];
    }
    #pragma unroll
    for (int it = 0; it < 4; ++it) {
        int e = it * 256 + tid, row = e >> 3, g = e & 7;
        gB[it] = &Bt[(size_t)(bn + row) * K + (g ^ (row & 7)) * 8];
    }

    f32x4 acc[RM][RN] = {};
    const int NT = K >> 6;   // 8

    #pragma unroll
    for (int it = 0; it < 2; ++it) gload16(gA[it], &As[0][(it * 256 + tid) * 8]);
    #pragma unroll
    for (int it = 0; it < 4; ++it) gload16(gB[it], &Bs[0][(it * 256 + tid) * 8]);
    __syncthreads();

    for (int t = 0; t < NT; ++t) {
        int cur = t & 1;
        if (t + 1 < NT) {
            #pragma unroll
            for (int it = 0; it < 2; ++it)
                gload16(gA[it] + (t + 1) * 64, &As[cur ^ 1][(it * 256 + tid) * 8]);
            #pragma unroll
            for (int it = 0; it < 4; ++it)
                gload16(gB[it] + (t + 1) * 64, &Bs[cur ^ 1][(it * 256 + tid) * 8]);
        }
        #pragma unroll
        for (int s = 0; s < 2; ++s) {
            bf16x8 a[RM], b[RN];
            int g8 = ((s * 4 + lk) ^ (l15 & 7)) * 8;
            #pragma unroll
            for (int m = 0; m < RM; ++m) {
                int row = wr * 32 + m * 16 + l15;
                a[m] = *(const bf16x8*)&As[cur][row * 64 + g8];
            }
            #pragma unroll
            for (int n = 0; n < RN; ++n) {
                int row = wc * 64 + n * 16 + l15;
                b[n] = *(const bf16x8*)&Bs[cur][row * 64 + g8];
            }
            #pragma unroll
            for (int m = 0; m < RM; ++m)
                #pragma unroll
                for (int n = 0; n < RN; ++n)
                    acc[m][n] = __builtin_amdgcn_mfma_f32_16x16x32_bf16(a[m], b[n], acc[m][n], 0, 0, 0);
        }
        __syncthreads();
    }

    if (bn < DIM) {
        float eq[RN];
        #pragma unroll
        for (int n = 0; n < RN; ++n)
            eq[n] = expf(qb[bn + wc * 64 + n * 16 + l15]);
        #pragma unroll
        for (int m = 0; m < RM; ++m) {
            #pragma unroll
            for (int r = 0; r < 4; ++r) {
                float s = 0.f;
                #pragma unroll
                for (int n = 0; n < RN; ++n) {
                    float x = acc[m][n][r] - eq[n];
                    s += 1.0f / (1.0f + expf(-x));
                }
                s *= (1.0f / 64.0f);
                #pragma unroll
                for (int off = 1; off < 16; off <<= 1) s += __shfl_xor(s, off);
                if (l15 == 0)
                    qsums[wc][wr * 32 + m * 16 + lk * 4 + r] = s;
            }
        }
        __syncthreads();
        if (tid < 128) {
            int hh = tid >> 6, row = tid & 63;
            qs[(size_t)(bm + row) * NH + (bn >> 6) + hh] = qsums[hh][row];
        }
    } else {
        // V -> vT[col][t] via LDS transpose (Bs dead after last barrier)
        unsigned short* tb = &Bs[0][0];        // [128 col][72 t-pad]
        #pragma unroll
        for (int m = 0; m < RM; ++m) {
            int trow0 = wr * 32 + m * 16 + lk * 4;
            #pragma unroll
            for (int n = 0; n < RN; ++n) {
                int col = wc * 64 + n * 16 + l15;
                float bs = Vb[bn - DIM + col];
                bf16 tmp[4];
                #pragma unroll
                for (int r = 0; r < 4; ++r)
                    tmp[r] = __float2bfloat16(acc[m][n][r] + bs);
                *(uint2*)&tb[col * 72 + trow0] = *(uint2*)tmp;
            }
        }
        __syncthreads();
        #pragma unroll
        for (int rep = 0; rep < 8; ++rep) {
            int idx = rep * 256 + tid;        // < 2048
            int col = idx >> 4;               // 0..127
            int t4  = (idx & 15) * 4;         // 0..60
            uint2 v = *(uint2*)&tb[col * 72 + t4];
            *(uint2*)&vT[(size_t)(bn - DIM + col) * ROWS + bm + t4] = v;
        }
    }
}

// ---- wpart_mfma: per (bh, kc) one BK=64 t-slab; partials stored bf16 ----
__global__ __launch_bounds__(256) void wpart_mfma(const bf16* __restrict__ timefT,
                                                  const bf16* __restrict__ vT,
                                                  bf16* __restrict__ wpart)
{
    __shared__ unsigned short As[128 * 64];
    __shared__ unsigned short Bs[64 * 64];

    int bh = blockIdx.x;              // 0..15
    int kc = blockIdx.y;              // 0..31
    int b = bh >> 3, h = bh & 7;
    int tid  = threadIdx.x;
    int lane = tid & 63, wave = tid >> 6;
    int wr = wave >> 1, wc = wave & 1;
    int l15 = lane & 15, lk = lane >> 4;
    int k0 = kc * 64;

    const bf16* Abase = timefT + (size_t)h * (128 * LSEQ) + k0;
    const bf16* Bbase = vT + (size_t)h * 64 * ROWS + (size_t)b * LSEQ + k0;

    #pragma unroll
    for (int it = 0; it < 4; ++it) {
        int e = it * 256 + tid, row = e >> 3, g = e & 7;
        gload16(Abase + (size_t)row * LSEQ + (g ^ (row & 7)) * 8, &As[e * 8]);
    }
    #pragma unroll
    for (int it = 0; it < 2; ++it) {
        int e = it * 256 + tid, row = e >> 3, g = e & 7;
        gload16(Bbase + (size_t)row * ROWS + (g ^ (row & 7)) * 8, &Bs[e * 8]);
    }
    __syncthreads();

    f32x4 acc[4][2] = {};
    #pragma unroll
    for (int s = 0; s < 2; ++s) {
        bf16x8 a[4], bv[2];
        int g8 = ((s * 4 + lk) ^ (l15 & 7)) * 8;
        #pragma unroll
        for (int m = 0; m < 4; ++m) {
            int row = wr * 64 + m * 16 + l15;
            a[m] = *(const bf16x8*)&As[row * 64 + g8];
        }
        #pragma unroll
        for (int n = 0; n < 2; ++n) {
            int row = wc * 32 + n * 16 + l15;
            bv[n] = *(const bf16x8*)&Bs[row * 64 + g8];
        }
        #pragma unroll
        for (int m = 0; m < 4; ++m)
            #pragma unroll
            for (int n = 0; n < 2; ++n)
                acc[m][n] = __builtin_amdgcn_mfma_f32_16x16x32_bf16(a[m], bv[n], acc[m][n], 0, 0, 0);
    }

    bf16* wp = wpart + ((size_t)(kc * 16 + bh)) * (HDIM * TF);
    #pragma unroll
    for (int m = 0; m < 4; ++m) {
        int gd0 = wr * 64 + m * 16 + lk * 4;
        #pragma unroll
        for (int n = 0; n < 2; ++n) {
            int ghd = wc * 32 + n * 16 + l15;
            bf16 tmp[4];
            #pragma unroll
            for (int r = 0; r < 4; ++r) tmp[r] = __float2bfloat16(acc[m][n][r]);
            *(uint2*)&wp[ghd * TF + gd0] = *(uint2*)tmp;
        }
    }
}

// ---- wred: sum 32 bf16 partials -> WT bf16, 8 elems/thread ----
__global__ __launch_bounds__(256) void wred_kernel(const bf16* __restrict__ wpart,
                                                   bf16* __restrict__ WT)
{
    int i8 = (blockIdx.x * 256 + threadIdx.x) * 8;   // < 131072
    float s[8] = {};
    #pragma unroll
    for (int kc = 0; kc < KCH; ++kc) {
        uint4 u = *(const uint4*)&wpart[(size_t)kc * 131072 + i8];
        const bf16* p = (const bf16*)&u;
        #pragma unroll
        for (int r = 0; r < 8; ++r) s[r] += b2f(p[r]);
    }
    bf16 o[8];
    #pragma unroll
    for (int r = 0; r < 8; ++r) o[r] = __float2bfloat16(s[r]);
    *(uint4*)&WT[i8] = *(uint4*)o;
}

// ---- comb[b,l,h,:] = qs[l,h]*mask[l] * (time[l,h,:] @ WT[bh]^T), MFMA ------
__global__ __launch_bounds__(256) void comb_mfma(const bf16* __restrict__ timef,
                                                 const bf16* __restrict__ WT,
                                                 const float* __restrict__ qs,
                                                 const float* __restrict__ mask,
                                                 bf16* __restrict__ comb)
{
    int bh = blockIdx.x;
    int b = bh >> 3, h = bh & 7;
    int lane = threadIdx.x & 63, wave = threadIdx.x >> 6;
    int l15 = lane & 15, lk = lane >> 4;
    int lbase = blockIdx.y * 64 + wave * 16;

    const bf16* wt = WT + (size_t)bh * (HDIM * TF);

    f32x4 acc[4] = {};
    #pragma unroll
    for (int ks = 0; ks < 4; ++ks) {
        int kt = ks * 32;
        bf16x8 a, bf[4];
        a = *(const bf16x8*)&timef[((size_t)(lbase + l15) * NH + h) * TF + kt + lk * 8];
        #pragma unroll
        for (int n = 0; n < 4; ++n)
            bf[n] = *(const bf16x8*)&wt[(size_t)(n * 16 + l15) * TF + kt + lk * 8];
        #pragma unroll
        for (int n = 0; n < 4; ++n)
            acc[n] = __builtin_amdgcn_mfma_f32_16x16x32_bf16(a, bf[n], acc[n], 0, 0, 0);
    }

    #pragma unroll
    for (int r = 0; r < 4; ++r) {
        int l = lbase + lk * 4 + r;
        int row = b * LSEQ + l;
        float q = qs[(size_t)row * NH + h] * mask[row];
        #pragma unroll
        for (int n = 0; n < 4; ++n) {
            int hd = n * 16 + l15;
            comb[(size_t)row * DIM + h * HDIM + hd] = __float2bfloat16(q * acc[n][r]);
        }
    }
}

// ---------------- LayerNorm over last dim (512) ----------------
template<int OUTBF>
__global__ __launch_bounds__(256) void ln_kernel(const float* __restrict__ X,
                                                 const float* __restrict__ g,
                                                 const float* __restrict__ bta,
                                                 float* __restrict__ outf,
                                                 bf16* __restrict__ outb)
{
    int row = blockIdx.x;
    const float* x = X + (size_t)row * DIM;
    float v0 = x[threadIdx.x], v1 = x[threadIdx.x + 256];
    float s = v0 + v1, s2 = v0 * v0 + v1 * v1;
    #pragma unroll
    for (int off = 1; off < 64; off <<= 1) {
        s  += __shfl_xor(s,  off);
        s2 += __shfl_xor(s2, off);
    }
    __shared__ float sh[2][4];
    int wave = threadIdx.x >> 6, lane = threadIdx.x & 63;
    if (lane == 0) { sh[0][wave] = s; sh[1][wave] = s2; }
    __syncthreads();
    s  = sh[0][0] + sh[0][1] + sh[0][2] + sh[0][3];
    s2 = sh[1][0] + sh[1][1] + sh[1][2] + sh[1][3];
    float mu  = s * (1.0f / DIM);
    float var = s2 * (1.0f / DIM) - mu * mu;
    float inv = rsqrtf(var + 1e-5f);
    int c0 = threadIdx.x, c1 = threadIdx.x + 256;
    float o0 = (v0 - mu) * inv * g[c0] + bta[c0];
    float o1 = (v1 - mu) * inv * g[c1] + bta[c1];
    if constexpr (OUTBF) {
        outb[(size_t)row * DIM + c0] = __float2bfloat16(o0);
        outb[(size_t)row * DIM + c1] = __float2bfloat16(o1);
    } else {
        outf[(size_t)row * DIM + c0] = o0;
        outf[(size_t)row * DIM + c1] = o1;
    }
}

extern "C" void kernel_launch(void* const* d_in, const int* in_sizes, int n_in,
                              void* d_out, int out_size, void* d_ws, size_t ws_size,
                              hipStream_t stream)
{
    const float* tensor = (const float*)d_in[0];
    const float* mask   = (const float*)d_in[1];
    const float* tang   = (const float*)d_in[2];
    const float* htd    = (const float*)d_in[3];
    const float* Qw     = (const float*)d_in[4];
    const float* qb     = (const float*)d_in[5];
    // d_in[6], d_in[7] (Kw, Kb) dead code
    const float* Vw     = (const float*)d_in[8];
    const float* Vb     = (const float*)d_in[9];
    const float* Ow     = (const float*)d_in[10];
    const float* Ob     = (const float*)d_in[11];
    const float* g1     = (const float*)d_in[12];
    const float* b1     = (const float*)d_in[13];
    const float* Win    = (const float*)d_in[14];
    const float* bin    = (const float*)d_in[15];
    const float* Wout   = (const float*)d_in[16];
    const float* bout   = (const float*)d_in[17];
    const float* g2     = (const float*)d_in[18];
    const float* b2     = (const float*)d_in[19];
    float* out = (float*)d_out;

    float* ws = (float*)d_ws;
    // Layout identical to round 13. NOTE: combb aliases tensorb (comb written at
    // step 5 kills tensorb) — step 6's residual therefore MUST read the original
    // f32 `tensor` input, never tensorb.
    bf16*  vT     = (bf16*)(ws + 0);
    bf16*  actb   = (bf16*)(ws + 0);
    bf16*  tensorb= (bf16*)(ws + 1048576);
    bf16*  combb  = tensorb;
    bf16*  timefb = (bf16*)(ws + 2097152);
    bf16*  timefT = (bf16*)(ws + 3145728);
    bf16*  interb = (bf16*)(ws + 3145728);
    bf16*  wpart  = (bf16*)(ws + 4194304);    // 32 x 131072 bf16 = 8 MB
    float* preLN1 = ws + 4194304;
    float* buf5   = ws + 6291456;
    bf16*  WTb    = (bf16*)(ws + 8388608);
    float* qs     = ws + 8454144;
    bf16*  QVwT   = (bf16*)(ws + 8486912);
    bf16*  QwT    = QVwT;
    bf16*  VwT    = QVwT + (size_t)512 * 512;
    bf16*  OwT    = (bf16*)(ws + 8749056);
    bf16*  WinT   = (bf16*)(ws + 8880128);
    bf16*  WoutT  = (bf16*)(ws + 9273344);

    // 1. setup
    setup_kernel<<<5376, 256, 0, stream>>>(tensor, tang, htd, Qw, Vw, Ow, Win, Wout,
                                           tensorb, timefb, timefT, QwT, VwT, OwT, WinT, WoutT);
    // 2. fused Q+V GEMM (64x128, BK=64, 512 blocks)
    gemm_qv<<<dim3(8, 64), 256, 0, stream>>>(tensorb, QVwT, qb, Vb, qs, vT);
    // 3. WT partials via MFMA (split-K 32, bf16 partials)
    wpart_mfma<<<dim3(16, KCH), 256, 0, stream>>>(timefT, vT, wpart);
    // 4. reduce -> WT bf16 (8 elems/thread)
    wred_kernel<<<64, 256, 0, stream>>>(wpart, WTb);
    // 5. comb via MFMA (512 blocks)
    comb_mfma<<<dim3(16, 32), 256, 0, stream>>>(timefb, WTb, qs, mask, combb);
    // 6. attn_out + residual(tensor f32) -> preLN1  (64x64, BK=128, 512 blocks)
    gemm_big<64, 64, 128, 2, float, float><<<dim3(8, 64), 256, 0, stream>>>(combb, OwT, Ob, tensor, preLN1, ROWS, DIM, DIM);
    // 7. LN1 -> interb bf16
    ln_kernel<1><<<ROWS, 256, 0, stream>>>(preLN1, g1, b1, nullptr, interb);
    // 8. FFN in + gelu -> bf16  (64x128, BK=64, 768 blocks)
    gemm_big<64, 128, 64, 3, bf16, float><<<dim3(12, 64), 256, 0, stream>>>(interb, WinT, bin, nullptr, actb, ROWS, LIND, DIM);
    // 9. FFN out + residual(interb)  (64x64, BK=128, 512 blocks)
    gemm_big<64, 64, 128, 4, float, bf16><<<dim3(8, 64), 256, 0, stream>>>(actb, WoutT, bout, interb, buf5, ROWS, DIM, LIND);
    // 10. LN2 -> f32 output
    ln_kernel<0><<<ROWS, 256, 0, stream>>>(buf5, g2, b2, out, nullptr);
}